// Round 1
// baseline (1793.541 us; speedup 1.0000x reference)
//
#include <hip/hip_runtime.h>
#include <hip/hip_bf16.h>
#include <stdint.h>

#define S_LEN  2048
#define BATCH  16
#define HDIM   512
#define HIDIM  1024
#define NLAYER 3
#define SCAN_C 32
#define SCAN_T 64

typedef __hip_bfloat16 bf16;
typedef __attribute__((ext_vector_type(8))) short bf16x8;
typedef __attribute__((ext_vector_type(4))) float f32x4;
typedef unsigned int u32;

// direct global->LDS, 16B per lane; LDS dest is wave-uniform base + lane*16
#define GLOAD16(gp, lp) __builtin_amdgcn_global_load_lds(                 \
    (const __attribute__((address_space(1))) void*)(gp),                  \
    (__attribute__((address_space(3))) void*)(lp), 16, 0, 0)

// ---------------------------------------------------------------- dtype probe
// flag=1: float buffers are f32; flag=0: bf16.
__global__ void probe_dtype(const unsigned short* __restrict__ w, int* __restrict__ flag)
{
  int cnt = 0;
  for (int i = threadIdx.x; i < 4096; i += 64) {
    unsigned short m = w[i] & 0x7FFF;
    if (m > 0x4080) cnt++;              // |x| > 4.0 (or inf/nan), integer compare
  }
  for (int o = 32; o; o >>= 1) cnt += __shfl_down(cnt, o, 64);
  if (threadIdx.x == 0) *flag = (cnt > 64) ? 1 : 0;
}

// ---------------------------------------------------------------- activation
__device__ __forceinline__ void av_calc(float hid, float gate, float& a, float& v) {
  a = 1.0f / (1.0f + __expf(gate));
  float z = 1.0f / (1.0f + __expf(-gate));
  float g = (hid >= 0.0f) ? (hid + 0.5f) : (1.0f / (1.0f + __expf(-hid)));
  v = z * g;
}

__device__ __forceinline__ short f2bs(float f) {
  bf16 h = (bf16)f;
  return *(short*)&h;
}

__device__ __forceinline__ bf16x8 pack8(float4 a, float4 b) {
  bf16x8 r;
  r[0] = f2bs(a.x); r[1] = f2bs(a.y); r[2] = f2bs(a.z); r[3] = f2bs(a.w);
  r[4] = f2bs(b.x); r[5] = f2bs(b.y); r[6] = f2bs(b.z); r[7] = f2bs(b.w);
  return r;
}

// ---------------------------------------------------------------- main GEMM (m97 structure)
// C[M,N] = A[M,K] * Bt[N,K]^T ; all bf16. M,N mult of 128; K mult of 32.
// global_load_lds width-16 staging, linear LDS, XCD-swizzled blocks (nwg%8==0).
__global__ __launch_bounds__(256, 3)
void gemm_lds(const bf16* __restrict__ A, const bf16* __restrict__ Bt,
              bf16* __restrict__ Cout, int K, int lda, int ldc)
{
  __shared__ bf16 As[128 * 32];
  __shared__ bf16 Bs[128 * 32];

  const int tid  = threadIdx.x;
  const int wave = tid >> 6;
  const int lane = tid & 63;

  // bijective XCD swizzle: hardware block h -> XCD h%8; give each XCD a
  // contiguous tile chunk (nwg is always a multiple of 8 at our shapes).
  const u32 nwg = gridDim.x * gridDim.y;
  const u32 hb  = blockIdx.y * gridDim.x + blockIdx.x;
  const u32 cpx = nwg >> 3;
  const u32 swz = (hb & 7u) * cpx + (hb >> 3);
  const int m0 = (int)(swz / gridDim.x) * 128;
  const int n0 = (int)(swz % gridDim.x) * 128;

  // staging: wave w issues 2 loads each for A and B; issue i covers rows
  // [(w*2+i)*16, +16): lane l -> row +(l>>2), k-chunk (l&3)*8 elements (16B)
  const int srow = wave * 32 + (lane >> 2);
  const int sk   = (lane & 3) * 8;
  const bf16* gA0 = A  + (long)(m0 + srow) * lda + sk;
  const bf16* gA1 = gA0 + 16 * (long)lda;
  const bf16* gB0 = Bt + (long)(n0 + srow) * K + sk;
  const bf16* gB1 = gB0 + 16 * (long)K;
  bf16* lA0 = &As[(wave * 2 + 0) * 512];
  bf16* lA1 = &As[(wave * 2 + 1) * 512];
  bf16* lB0 = &Bs[(wave * 2 + 0) * 512];
  bf16* lB1 = &Bs[(wave * 2 + 1) * 512];

  f32x4 acc[4][4];
#pragma unroll
  for (int i = 0; i < 4; i++)
#pragma unroll
    for (int j = 0; j < 4; j++)
#pragma unroll
      for (int r = 0; r < 4; r++) acc[i][j][r] = 0.0f;

  const int mBase = (wave >> 1) * 64;
  const int nBase = (wave & 1) * 64;
  const int fr = lane & 15;
  const int fq = (lane >> 4) * 8;

  for (int k0 = 0; k0 < K; k0 += 32) {
    GLOAD16(gA0, lA0);
    GLOAD16(gA1, lA1);
    GLOAD16(gB0, lB0);
    GLOAD16(gB1, lB1);
    gA0 += 32; gA1 += 32; gB0 += 32; gB1 += 32;
    __syncthreads();   // drains vmcnt(0): staged data visible to all waves

    bf16x8 afr[4], bfr[4];
#pragma unroll
    for (int mt = 0; mt < 4; mt++)
      afr[mt] = *(const bf16x8*)&As[(mBase + mt * 16 + fr) * 32 + fq];
#pragma unroll
    for (int nt = 0; nt < 4; nt++)
      bfr[nt] = *(const bf16x8*)&Bs[(nBase + nt * 16 + fr) * 32 + fq];

#pragma unroll
    for (int mt = 0; mt < 4; mt++)
#pragma unroll
      for (int nt = 0; nt < 4; nt++)
        acc[mt][nt] = __builtin_amdgcn_mfma_f32_16x16x32_bf16(afr[mt], bfr[nt], acc[mt][nt], 0, 0, 0);

    __syncthreads();   // all fragment reads done before next-iter staging
  }

  // C/D layout: col = lane&15, row = (lane>>4)*4 + reg
  const int orow = (lane >> 4) * 4;
  const int ocol = lane & 15;
#pragma unroll
  for (int mt = 0; mt < 4; mt++) {
#pragma unroll
    for (int nt = 0; nt < 4; nt++) {
      int gr = m0 + mBase + mt * 16 + orow;
      int gc = n0 + nBase + nt * 16 + ocol;
#pragma unroll
      for (int r = 0; r < 4; r++)
        Cout[(long)(gr + r) * ldc + gc] = (bf16)acc[mt][nt][r];
    }
  }
}

// ---------------------------------------------------------------- gather GEMM (embedding)
// C[M,N] = A[gidx[m],K] * Bt[N,K]^T + bias; A dtype per *flag (f32 or bf16).
template<int GATHER, int BIAS>
__global__ __launch_bounds__(256, 2)
void gemm_mfma(const void* __restrict__ Av, const bf16* __restrict__ Bt,
               bf16* __restrict__ Cout, const float* __restrict__ bias,
               const int* __restrict__ gidx, const int* __restrict__ flag,
               int M, int N, int K, int lda, int ldc)
{
  __shared__ bf16 As[128 * 32];
  __shared__ bf16 Bs[128 * 32];

  const int tid  = threadIdx.x;
  const int wave = tid >> 6;
  const int lane = tid & 63;
  const int m0 = blockIdx.y * 128;
  const int n0 = blockIdx.x * 128;

  const int seg0 = wave * 2, seg1 = seg0 + 1;
  const int lr = lane >> 2;
  const int ck = (lane & 3) * 8;
  const int rA0 = seg0 * 16 + lr;
  const int rA1 = seg1 * 16 + lr;

  const int af = GATHER ? *flag : 0;

  long ga0 = GATHER ? (long)gidx[m0 + rA0] : (long)(m0 + rA0);
  long ga1 = GATHER ? (long)gidx[m0 + rA1] : (long)(m0 + rA1);
  const bf16*  hA0 = (const bf16*)Av + ga0 * (long)lda + ck;
  const bf16*  hA1 = (const bf16*)Av + ga1 * (long)lda + ck;
  const float* qA0 = (const float*)Av + ga0 * (long)lda + ck;
  const float* qA1 = (const float*)Av + ga1 * (long)lda + ck;
  const bf16*  pB0 = Bt + (long)(n0 + rA0) * K + ck;
  const bf16*  pB1 = Bt + (long)(n0 + rA1) * K + ck;

  bf16* lA0 = &As[seg0 * 512 + lane * 8];
  bf16* lA1 = &As[seg1 * 512 + lane * 8];
  bf16* lB0 = &Bs[seg0 * 512 + lane * 8];
  bf16* lB1 = &Bs[seg1 * 512 + lane * 8];

  f32x4 acc[4][4];
#pragma unroll
  for (int i = 0; i < 4; i++)
#pragma unroll
    for (int j = 0; j < 4; j++)
#pragma unroll
      for (int r = 0; r < 4; r++) acc[i][j][r] = 0.0f;

  const int mBase = (wave >> 1) * 64;
  const int nBase = (wave & 1) * 64;
  const int fr = lane & 15;
  const int fq = (lane >> 4) * 8;

  for (int k0 = 0; k0 < K; k0 += 32) {
    bf16x8 va0, va1;
    if (GATHER && af) {
      float4 a0 = *(const float4*)(qA0 + k0);
      float4 a1 = *(const float4*)(qA0 + k0 + 4);
      float4 b0 = *(const float4*)(qA1 + k0);
      float4 b1 = *(const float4*)(qA1 + k0 + 4);
      va0 = pack8(a0, a1);
      va1 = pack8(b0, b1);
    } else {
      va0 = *(const bf16x8*)(hA0 + k0);
      va1 = *(const bf16x8*)(hA1 + k0);
    }
    bf16x8 vb0 = *(const bf16x8*)(pB0 + k0);
    bf16x8 vb1 = *(const bf16x8*)(pB1 + k0);
    __syncthreads();
    *(bf16x8*)lA0 = va0;
    *(bf16x8*)lA1 = va1;
    *(bf16x8*)lB0 = vb0;
    *(bf16x8*)lB1 = vb1;
    __syncthreads();

    bf16x8 afr[4], bfr[4];
#pragma unroll
    for (int mt = 0; mt < 4; mt++)
      afr[mt] = *(const bf16x8*)&As[(mBase + mt * 16 + fr) * 32 + fq];
#pragma unroll
    for (int nt = 0; nt < 4; nt++)
      bfr[nt] = *(const bf16x8*)&Bs[(nBase + nt * 16 + fr) * 32 + fq];

#pragma unroll
    for (int mt = 0; mt < 4; mt++)
#pragma unroll
      for (int nt = 0; nt < 4; nt++)
        acc[mt][nt] = __builtin_amdgcn_mfma_f32_16x16x32_bf16(afr[mt], bfr[nt], acc[mt][nt], 0, 0, 0);
  }

  const int orow = (lane >> 4) * 4;
  const int ocol = lane & 15;
#pragma unroll
  for (int mt = 0; mt < 4; mt++) {
#pragma unroll
    for (int nt = 0; nt < 4; nt++) {
      int gr = m0 + mBase + mt * 16 + orow;
      int gc = n0 + nBase + nt * 16 + ocol;
      float bv = BIAS ? bias[gc] : 0.0f;
#pragma unroll
      for (int r = 0; r < 4; r++) {
        float v = acc[mt][nt][r] + bv;
        Cout[(long)(gr + r) * ldc + gc] = (bf16)v;
      }
    }
  }
}

// ---------------------------------------------------------------- converters
__global__ __launch_bounds__(256)
void transpose_conv(const void* __restrict__ in, bf16* __restrict__ out,
                    const int* __restrict__ flag, int R, int C)
{
  __shared__ float tile[32][33];
  int f = *flag;
  int x = blockIdx.x * 32 + threadIdx.x;
  int yb = blockIdx.y * 32;
#pragma unroll
  for (int i = threadIdx.y; i < 32; i += 8) {
    long idx = (long)(yb + i) * C + x;
    tile[i][threadIdx.x] = f ? ((const float*)in)[idx] : (float)((const bf16*)in)[idx];
  }
  __syncthreads();
  int x2 = yb + threadIdx.x;
  int y2b = blockIdx.x * 32;
#pragma unroll
  for (int i = threadIdx.y; i < 32; i += 8)
    out[(long)(y2b + i) * R + x2] = (bf16)tile[threadIdx.x][i];
}

// dual-base transpose+convert: picks f32 or bf16 source per flag
__global__ __launch_bounds__(256)
void transpose_conv2(const void* __restrict__ in32, const void* __restrict__ in16,
                     bf16* __restrict__ out, const int* __restrict__ flag, int R, int C)
{
  __shared__ float tile[32][33];
  int f = *flag;
  int x = blockIdx.x * 32 + threadIdx.x;
  int yb = blockIdx.y * 32;
#pragma unroll
  for (int i = threadIdx.y; i < 32; i += 8) {
    long idx = (long)(yb + i) * C + x;
    tile[i][threadIdx.x] = f ? ((const float*)in32)[idx] : (float)((const bf16*)in16)[idx];
  }
  __syncthreads();
  int x2 = yb + threadIdx.x;
  int y2b = blockIdx.x * 32;
#pragma unroll
  for (int i = threadIdx.y; i < 32; i += 8)
    out[(long)(y2b + i) * R + x2] = (bf16)tile[threadIdx.x][i];
}

__global__ __launch_bounds__(256)
void conv_to_f32(const void* __restrict__ in, float* __restrict__ out,
                 const int* __restrict__ flag, int n)
{
  int i = blockIdx.x * blockDim.x + threadIdx.x;
  if (i >= n) return;
  out[i] = (*flag) ? ((const float*)in)[i] : (float)((const bf16*)in)[i];
}

// ---------------------------------------------------------------- scan
__global__ __launch_bounds__(256)
void scan_pass1(const bf16* __restrict__ HG, float* __restrict__ Ab, float* __restrict__ Pb)
{
  int tid = blockIdx.x * blockDim.x + threadIdx.x;
  int c  = tid & (HIDIM - 1);
  int bj = tid >> 10;
  int j  = bj & (SCAN_C - 1);
  int b  = bj >> 5;
  const bf16* base = HG + ((long)(b * S_LEN + j * SCAN_T)) * 2048 + c;
  float A = 1.0f, P = 0.0f;
#pragma unroll 4
  for (int t = 0; t < SCAN_T; t++) {
    float hid = (float)base[(long)t * 2048];
    float gt  = (float)base[(long)t * 2048 + 1024];
    float a, v; av_calc(hid, gt, a, v);
    A *= a;
    P = fmaf(a, P, v);
  }
  Ab[tid] = A;
  Pb[tid] = P;
}

__global__ __launch_bounds__(256)
void scan_pass2(const float* __restrict__ Ab, float* __restrict__ Pb)
{
  int tid = blockIdx.x * blockDim.x + threadIdx.x;
  int c = tid & (HIDIM - 1);
  int b = tid >> 10;
  float h = 0.0f;
  for (int j = 0; j < SCAN_C; j++) {
    long i = ((long)(b * SCAN_C + j) << 10) + c;
    float A = Ab[i];
    float P = Pb[i];
    Pb[i] = h;
    h = fmaf(A, h, P);
  }
}

__global__ __launch_bounds__(256)
void scan_pass3(bf16* __restrict__ HG, const float* __restrict__ Pb)
{
  int tid = blockIdx.x * blockDim.x + threadIdx.x;
  int c  = tid & (HIDIM - 1);
  int bj = tid >> 10;
  int j  = bj & (SCAN_C - 1);
  int b  = bj >> 5;
  bf16* base = HG + ((long)(b * S_LEN + j * SCAN_T)) * 2048 + c;
  float h = Pb[tid];
#pragma unroll 4
  for (int t = 0; t < SCAN_T; t++) {
    float hid = (float)base[(long)t * 2048];
    float gt  = (float)base[(long)t * 2048 + 1024];
    float a, v; av_calc(hid, gt, a, v);
    h = fmaf(a, h, v);
    base[(long)t * 2048] = (bf16)h;
  }
}

// ---------------------------------------------------------------- shift / output
__global__ __launch_bounds__(256)
void rev_build(const bf16* __restrict__ X, bf16* __restrict__ X2, const int* __restrict__ lens)
{
  int bt = blockIdx.x;
  int b = bt >> 11;
  int t = bt & (S_LEN - 1);
  int pad = S_LEN - lens[b];
  int src = S_LEN - 1 - ((t + pad) & (S_LEN - 1));
  const u32* s = (const u32*)(X + (long)(b * S_LEN + src) * HDIM);
  u32* d = (u32*)(X2 + (long)(b * S_LEN + t) * HDIM);
  d[threadIdx.x] = s[threadIdx.x];
}

__global__ __launch_bounds__(256)
void finalize_out(const bf16* __restrict__ X, const bf16* __restrict__ X2,
                  const int* __restrict__ lens, const int* __restrict__ flag,
                  void* __restrict__ out)
{
  int bt = blockIdx.x;
  int b = bt >> 11;
  int t = bt & (S_LEN - 1);
  int pad = S_LEN - lens[b];
  int src = S_LEN - 1 - ((t + pad) & (S_LEN - 1));
  const bf16* sf = X  + (long)(b * S_LEN + t) * HDIM;
  const bf16* sr = X2 + (long)(b * S_LEN + src) * HDIM;
  long ro = (long)(b * S_LEN + t) * 1024;
  if (*flag) {
    float* d = (float*)out + ro;
    for (int c = threadIdx.x; c < 512; c += 256) {
      d[c]       = (float)sf[c];
      d[512 + c] = (float)sr[c];
    }
  } else {
    bf16* d = (bf16*)out + ro;
    for (int c = threadIdx.x; c < 512; c += 256) {
      d[c]       = sf[c];
      d[512 + c] = sr[c];
    }
  }
}

__global__ __launch_bounds__(256)
void seq_out_k(const bf16* __restrict__ X, const bf16* __restrict__ X2,
               const int* __restrict__ lens, const int* __restrict__ flag,
               void* __restrict__ out)
{
  int b = blockIdx.x;
  int t = lens[b] - 1;
  const bf16* sf = X  + (long)(b * S_LEN + t) * HDIM;
  const bf16* sr = X2 + (long)(b * S_LEN + 0) * HDIM;
  long off = (long)BATCH * S_LEN * 1024 + (long)b * 1024;
  if (*flag) {
    float* d = (float*)out + off;
    for (int c = threadIdx.x; c < 512; c += 256) {
      d[c]       = (float)sf[c];
      d[512 + c] = (float)sr[c];
    }
  } else {
    bf16* d = (bf16*)out + off;
    for (int c = threadIdx.x; c < 512; c += 256) {
      d[c]       = sf[c];
      d[512 + c] = sr[c];
    }
  }
}

// ---------------------------------------------------------------- launch
extern "C" void kernel_launch(void* const* d_in, const int* in_sizes, int n_in,
                              void* d_out, int out_size, void* d_ws, size_t ws_size,
                              hipStream_t stream)
{
  (void)in_sizes; (void)n_in; (void)out_size;
  const int* x_source = (const int*)d_in[0];
  const int* x_len    = (const int*)d_in[1];
  const void* emb     = d_in[2];
  const void* W_er    = d_in[3];
  const void* b_er    = d_in[4];
  const void* W_hg[2]  = { d_in[5], d_in[7] };   // [3,512,2048]
  const void* W_out[2] = { d_in[6], d_in[8] };   // [3,1024,512]

  char* ws = (char*)d_ws;
  size_t off = 0;
  auto alloc = [&](size_t bytes) -> char* {
    char* p = ws + off;
    off += (bytes + 255) & ~(size_t)255;
    return p;
  };
  auto a256 = [](size_t b) -> size_t { return (b + 255) & ~(size_t)255; };

  int*   flag = (int*)  alloc(256);
  float* berF = (float*)alloc(512 * 4);
  bf16*  WerT = (bf16*) alloc((size_t)512 * 512 * 2);
  bf16*  X    = (bf16*) alloc((size_t)BATCH * S_LEN * HDIM * 2);   // fwd acts, 32 MB
  bf16*  X2   = (bf16*) alloc((size_t)BATCH * S_LEN * HDIM * 2);   // rev acts, 32 MB
  bf16* WhgT[2][NLAYER];
  bf16* WoutT[2][NLAYER];
  for (int d = 0; d < 2; d++)
    for (int l = 0; l < NLAYER; l++) {
      WhgT[d][l]  = (bf16*)alloc((size_t)2048 * 512 * 2);
      WoutT[d][l] = (bf16*)alloc((size_t)512 * 1024 * 2);
    }

  size_t fixedEnd = off;
  int bch = 16;
  while (bch > 1) {
    size_t need = fixedEnd
      + a256((size_t)bch * S_LEN * 2048 * 2)
      + 2 * a256((size_t)bch * SCAN_C * HIDIM * 4);
    if (need <= ws_size) break;
    bch >>= 1;
  }
  bf16*  HG = (bf16*) alloc((size_t)bch * S_LEN * 2048 * 2);
  float* Ab = (float*)alloc((size_t)bch * SCAN_C * HIDIM * 4);
  float* Pb = (float*)alloc((size_t)bch * SCAN_C * HIDIM * 4);

  probe_dtype<<<1, 64, 0, stream>>>((const unsigned short*)emb, flag);

  conv_to_f32<<<2, 256, 0, stream>>>(b_er, berF, flag, 512);
  dim3 tb(32, 8);
  transpose_conv<<<dim3(16, 16), tb, 0, stream>>>(W_er, WerT, flag, 512, 512);
  for (int d = 0; d < 2; d++)
    for (int l = 0; l < NLAYER; l++) {
      const char* hg32 = (const char*)W_hg[d] + (size_t)l * 512 * 2048 * 4;
      const char* hg16 = (const char*)W_hg[d] + (size_t)l * 512 * 2048 * 2;
      const char* wo32 = (const char*)W_out[d] + (size_t)l * 1024 * 512 * 4;
      const char* wo16 = (const char*)W_out[d] + (size_t)l * 1024 * 512 * 2;
      transpose_conv2<<<dim3(2048 / 32, 512 / 32), tb, 0, stream>>>(hg32, hg16, WhgT[d][l], flag, 512, 2048);
      transpose_conv2<<<dim3(512 / 32, 1024 / 32), tb, 0, stream>>>(wo32, wo16, WoutT[d][l], flag, 1024, 512);
    }

  // x_emb = emb[x_source] @ W_er + b_er -> X (bf16)   (gather path, dtype via flag)
  gemm_mfma<1, 1><<<dim3(4, (BATCH * S_LEN) / 128), 256, 0, stream>>>(
      emb, WerT, X, berF, x_source, flag, BATCH * S_LEN, 512, 512, 512, 512);

  rev_build<<<BATCH * S_LEN, 256, 0, stream>>>(X, X2, x_len);

  for (int d = 0; d < 2; d++) {
    bf16* Xd = d ? X2 : X;
    for (int l = 0; l < NLAYER; l++) {
      for (int cb = 0; cb < BATCH / bch; cb++) {
        bf16* Ain = Xd + (size_t)cb * bch * S_LEN * HDIM;
        int Mrows = bch * S_LEN;
        // HG = Ain @ W_hg   [Mrows,512] x [512,2048]
        gemm_lds<<<dim3(16, Mrows / 128), 256, 0, stream>>>(
            Ain, WhgT[d][l], HG, 512, 512, 2048);
        int nthr = bch * SCAN_C * HIDIM;
        scan_pass1<<<nthr / 256, 256, 0, stream>>>(HG, Ab, Pb);
        scan_pass2<<<(bch * HIDIM) / 256, 256, 0, stream>>>(Ab, Pb);
        scan_pass3<<<nthr / 256, 256, 0, stream>>>(HG, Pb);
        // Ain = h @ W_out   [Mrows,1024(stride 2048)] x [1024,512]
        gemm_lds<<<dim3(4, Mrows / 128), 256, 0, stream>>>(
            HG, WoutT[d][l], Ain, 1024, 2048, 512);
      }
    }
  }

  finalize_out<<<BATCH * S_LEN, 256, 0, stream>>>(X, X2, x_len, flag, d_out);
  seq_out_k<<<BATCH, 256, 0, stream>>>(X, X2, x_len, flag, d_out);
}

// Round 2
// 1777.095 us; speedup vs baseline: 1.0093x; 1.0093x over previous
//
#include <hip/hip_runtime.h>
#include <hip/hip_bf16.h>
#include <stdint.h>

#define S_LEN  2048
#define BATCH  16
#define HDIM   512
#define HIDIM  1024
#define NLAYER 3
#define SCAN_C 32
#define SCAN_T 64

typedef __hip_bfloat16 bf16;
typedef __attribute__((ext_vector_type(8))) short bf16x8;
typedef __attribute__((ext_vector_type(4))) float f32x4;
typedef unsigned int u32;

// direct global->LDS, 16B per lane; LDS dest is wave-uniform base + lane*16
#define GLOAD16(gp, lp) __builtin_amdgcn_global_load_lds(                 \
    (const __attribute__((address_space(1))) void*)(gp),                  \
    (__attribute__((address_space(3))) void*)(lp), 16, 0, 0)

#define FENCE asm volatile("" ::: "memory")
#define BAR   do { FENCE; __builtin_amdgcn_s_barrier(); FENCE; } while (0)
#define VMCNT(n) asm volatile("s_waitcnt vmcnt(" #n ")" ::: "memory")

// ---------------------------------------------------------------- dtype probe
// flag=1: float buffers are f32; flag=0: bf16.
__global__ void probe_dtype(const unsigned short* __restrict__ w, int* __restrict__ flag)
{
  int cnt = 0;
  for (int i = threadIdx.x; i < 4096; i += 64) {
    unsigned short m = w[i] & 0x7FFF;
    if (m > 0x4080) cnt++;              // |x| > 4.0 (or inf/nan), integer compare
  }
  for (int o = 32; o; o >>= 1) cnt += __shfl_down(cnt, o, 64);
  if (threadIdx.x == 0) *flag = (cnt > 64) ? 1 : 0;
}

// ---------------------------------------------------------------- activation
__device__ __forceinline__ void av_calc(float hid, float gate, float& a, float& v) {
  a = 1.0f / (1.0f + __expf(gate));
  float z = 1.0f / (1.0f + __expf(-gate));
  float g = (hid >= 0.0f) ? (hid + 0.5f) : (1.0f / (1.0f + __expf(-hid)));
  v = z * g;
}

__device__ __forceinline__ short f2bs(float f) {
  bf16 h = (bf16)f;
  return *(short*)&h;
}

__device__ __forceinline__ bf16x8 pack8(float4 a, float4 b) {
  bf16x8 r;
  r[0] = f2bs(a.x); r[1] = f2bs(a.y); r[2] = f2bs(a.z); r[3] = f2bs(a.w);
  r[4] = f2bs(b.x); r[5] = f2bs(b.y); r[6] = f2bs(b.z); r[7] = f2bs(b.w);
  return r;
}

// ================================================================ 8-phase 256^2 GEMM
// C[M,N] = A[M,K] * Bt[N,K]^T ; bf16. M,N mult of 256; K mult of 128.
// T2 swizzle: physical LDS holds logical (row, colbyte^((row&7)<<4)); the
// global SOURCE address is inverse-swizzled so global_load_lds (linear dest)
// lands data in swizzled order; ds_read applies the same XOR (rule 21).

__device__ __forceinline__ void stage_half(const bf16* __restrict__ G, int row0, int ld,
                                           int kbase, char* lhalf, int tid)
{
  // 128 rows x 64 cols, 2 gloads/thread (64 rows each)
  const int r  = tid >> 3;                                   // 0..63
  const int cc = (((tid & 7) ^ ((tid >> 3) & 7)) << 3);      // swizzled col chunk (elems)
  const bf16* g0 = G + (long)(row0 + r) * ld + (kbase + cc);
  char* l = lhalf + ((tid >> 6) << 10);                      // wave-uniform base
  GLOAD16(g0, l);
  GLOAD16(g0 + (long)64 * ld, l + 8192);
}

__device__ __forceinline__ bf16x8 frag_ld(const char* base, int Rl, int cb) {
  return *(const bf16x8*)(base + Rl * 128 + (cb ^ ((Rl & 7) << 4)));
}

__global__ __launch_bounds__(512, 2)
void gemm8(const bf16* __restrict__ A, const bf16* __restrict__ Bt,
           bf16* __restrict__ Cout, int K, int lda, int ldc)
{
  extern __shared__ char lds[];          // 128 KiB: buf0{A,B} buf1{A,B}

  const int tid  = threadIdx.x;
  const int wave = tid >> 6;
  const int lane = tid & 63;
  const int wm = wave >> 2;              // 0..1  (row half)
  const int wn = wave & 3;               // 0..3  (col quarter)

  // bijective XCD swizzle (nwg % 8 == 0 at all our shapes)
  const u32 nwg = gridDim.x * gridDim.y;
  const u32 hb  = blockIdx.y * gridDim.x + blockIdx.x;
  const u32 cpx = nwg >> 3;
  const u32 swz = (hb & 7u) * cpx + (hb >> 3);
  const int m0 = (int)(swz / gridDim.x) * 256;
  const int n0 = (int)(swz % gridDim.x) * 256;

  char* A0 = lds;                        // buf0 A 32K
  char* B0 = lds + 32768;                // buf0 B 32K
  char* A1 = lds + 65536;                // buf1 A 32K
  char* B1 = lds + 98304;                // buf1 B 32K

  const int fr = lane & 15;
  const int qh = lane >> 4;              // 0..3
  const int cqh = qh * 16;               // colbyte base of this lane's k-chunk

  f32x4 acc[8][4];
#pragma unroll
  for (int i = 0; i < 8; i++)
#pragma unroll
    for (int j = 0; j < 4; j++)
#pragma unroll
      for (int r = 0; r < 4; r++) acc[i][j][r] = 0.0f;

  const int NJ = K >> 7;                 // K / 128 (2 BK=64 tiles per iter)

  // ---- prologue: tile0 full -> buf0 ; tile1 B halves -> buf1 (12 loads/thread)
  stage_half(A,  m0,       lda, 0,  A0,         tid);
  stage_half(A,  m0 + 128, lda, 0,  A0 + 16384, tid);
  stage_half(Bt, n0,       K,   0,  B0,         tid);
  stage_half(Bt, n0 + 128, K,   0,  B0 + 16384, tid);
  stage_half(Bt, n0,       K,   64, B1,         tid);
  stage_half(Bt, n0 + 128, K,   64, B1 + 16384, tid);
  VMCNT(4);                              // tile0 landed; tile1-B stays in flight
  BAR;

  for (int j = 0; j < NJ; ++j) {
    const int last = (j == NJ - 1);
    const int kO  = (2 * j + 1) * 64;    // odd tile kbase (always valid)
    const int kE2 = (2 * j + 2) * 64;    // next even tile kbase
    const int kO2 = (2 * j + 3) * 64;    // next odd tile kbase

    // ======== even tile (buf0): phases 1-4 ========
    {
      bf16x8 bfrag[4][2];
#pragma unroll
      for (int q = 0; q < 4; ++q) {
        if (q == 0) {
#pragma unroll
          for (int nt = 0; nt < 4; ++nt)
#pragma unroll
            for (int kk = 0; kk < 2; ++kk)
              bfrag[nt][kk] = frag_ld(B0, wn * 64 + nt * 16 + fr, kk * 64 + cqh);
        }
        bf16x8 afrag[2][2];
#pragma unroll
        for (int t = 0; t < 2; ++t)
#pragma unroll
          for (int kk = 0; kk < 2; ++kk)
            afrag[t][kk] = frag_ld(A0, wm * 128 + (2 * q + t) * 16 + fr, kk * 64 + cqh);

        // staging plan: ph1 = odd-tile A (4), ph2/ph3 = next-even B halves
        if (q == 0) {
          stage_half(A, m0,       lda, kO, A1,         tid);
          stage_half(A, m0 + 128, lda, kO, A1 + 16384, tid);
        } else if (q == 1) {
          if (!last) stage_half(Bt, n0,       K, kE2, B0,         tid);
        } else if (q == 2) {
          if (!last) stage_half(Bt, n0 + 128, K, kE2, B0 + 16384, tid);
        }

        BAR;
        __builtin_amdgcn_s_setprio(1);
#pragma unroll
        for (int t = 0; t < 2; ++t)
#pragma unroll
          for (int nt = 0; nt < 4; ++nt)
#pragma unroll
            for (int kk = 0; kk < 2; ++kk)
              acc[2 * q + t][nt] = __builtin_amdgcn_mfma_f32_16x16x32_bf16(
                  afrag[t][kk], bfrag[nt][kk], acc[2 * q + t][nt], 0, 0, 0);
        __builtin_amdgcn_s_setprio(0);
        if (q == 3) {                    // phase 4: odd tile must be fully landed
          if (last) { VMCNT(0); } else { VMCNT(4); }
        }
        BAR;
      }
    }

    // ======== odd tile (buf1): phases 5-8 ========
    {
      bf16x8 bfrag[4][2];
#pragma unroll
      for (int q = 0; q < 4; ++q) {
        if (q == 0) {
#pragma unroll
          for (int nt = 0; nt < 4; ++nt)
#pragma unroll
            for (int kk = 0; kk < 2; ++kk)
              bfrag[nt][kk] = frag_ld(B1, wn * 64 + nt * 16 + fr, kk * 64 + cqh);
        }
        bf16x8 afrag[2][2];
#pragma unroll
        for (int t = 0; t < 2; ++t)
#pragma unroll
          for (int kk = 0; kk < 2; ++kk)
            afrag[t][kk] = frag_ld(A1, wm * 128 + (2 * q + t) * 16 + fr, kk * 64 + cqh);

        // staging plan: ph5/ph6 = next-even A halves, ph7/ph8 = next-odd B halves
        if (!last) {
          if (q == 0)      stage_half(A,  m0,       lda, kE2, A0,         tid);
          else if (q == 1) stage_half(A,  m0 + 128, lda, kE2, A0 + 16384, tid);
          else if (q == 2) stage_half(Bt, n0,       K,   kO2, B1,         tid);
          else             stage_half(Bt, n0 + 128, K,   kO2, B1 + 16384, tid);
        }

        BAR;
        __builtin_amdgcn_s_setprio(1);
#pragma unroll
        for (int t = 0; t < 2; ++t)
#pragma unroll
          for (int nt = 0; nt < 4; ++nt)
#pragma unroll
            for (int kk = 0; kk < 2; ++kk)
              acc[2 * q + t][nt] = __builtin_amdgcn_mfma_f32_16x16x32_bf16(
                  afrag[t][kk], bfrag[nt][kk], acc[2 * q + t][nt], 0, 0, 0);
        __builtin_amdgcn_s_setprio(0);
        if (q == 3 && !last) { VMCNT(4); }   // next even tile fully landed
        BAR;
      }
    }
  }

  // epilogue: C/D layout col = lane&15, row = (lane>>4)*4 + reg
  const int orow = qh * 4;
#pragma unroll
  for (int mt = 0; mt < 8; ++mt) {
#pragma unroll
    for (int nt = 0; nt < 4; ++nt) {
      int gr = m0 + wm * 128 + mt * 16 + orow;
      int gc = n0 + wn * 64 + nt * 16 + fr;
#pragma unroll
      for (int r = 0; r < 4; ++r)
        Cout[(long)(gr + r) * ldc + gc] = (bf16)acc[mt][nt][r];
    }
  }
}

// ---------------------------------------------------------------- gather GEMM (embedding)
// C[M,N] = A[gidx[m],K] * Bt[N,K]^T + bias; A dtype per *flag (f32 or bf16).
template<int GATHER, int BIAS>
__global__ __launch_bounds__(256, 2)
void gemm_mfma(const void* __restrict__ Av, const bf16* __restrict__ Bt,
               bf16* __restrict__ Cout, const float* __restrict__ bias,
               const int* __restrict__ gidx, const int* __restrict__ flag,
               int M, int N, int K, int lda, int ldc)
{
  __shared__ bf16 As[128 * 32];
  __shared__ bf16 Bs[128 * 32];

  const int tid  = threadIdx.x;
  const int wave = tid >> 6;
  const int lane = tid & 63;
  const int m0 = blockIdx.y * 128;
  const int n0 = blockIdx.x * 128;

  const int seg0 = wave * 2, seg1 = seg0 + 1;
  const int lr = lane >> 2;
  const int ck = (lane & 3) * 8;
  const int rA0 = seg0 * 16 + lr;
  const int rA1 = seg1 * 16 + lr;

  const int af = GATHER ? *flag : 0;

  long ga0 = GATHER ? (long)gidx[m0 + rA0] : (long)(m0 + rA0);
  long ga1 = GATHER ? (long)gidx[m0 + rA1] : (long)(m0 + rA1);
  const bf16*  hA0 = (const bf16*)Av + ga0 * (long)lda + ck;
  const bf16*  hA1 = (const bf16*)Av + ga1 * (long)lda + ck;
  const float* qA0 = (const float*)Av + ga0 * (long)lda + ck;
  const float* qA1 = (const float*)Av + ga1 * (long)lda + ck;
  const bf16*  pB0 = Bt + (long)(n0 + rA0) * K + ck;
  const bf16*  pB1 = Bt + (long)(n0 + rA1) * K + ck;

  bf16* lA0 = &As[seg0 * 512 + lane * 8];
  bf16* lA1 = &As[seg1 * 512 + lane * 8];
  bf16* lB0 = &Bs[seg0 * 512 + lane * 8];
  bf16* lB1 = &Bs[seg1 * 512 + lane * 8];

  f32x4 acc[4][4];
#pragma unroll
  for (int i = 0; i < 4; i++)
#pragma unroll
    for (int j = 0; j < 4; j++)
#pragma unroll
      for (int r = 0; r < 4; r++) acc[i][j][r] = 0.0f;

  const int mBase = (wave >> 1) * 64;
  const int nBase = (wave & 1) * 64;
  const int fr = lane & 15;
  const int fq = (lane >> 4) * 8;

  for (int k0 = 0; k0 < K; k0 += 32) {
    bf16x8 va0, va1;
    if (GATHER && af) {
      float4 a0 = *(const float4*)(qA0 + k0);
      float4 a1 = *(const float4*)(qA0 + k0 + 4);
      float4 b0 = *(const float4*)(qA1 + k0);
      float4 b1 = *(const float4*)(qA1 + k0 + 4);
      va0 = pack8(a0, a1);
      va1 = pack8(b0, b1);
    } else {
      va0 = *(const bf16x8*)(hA0 + k0);
      va1 = *(const bf16x8*)(hA1 + k0);
    }
    bf16x8 vb0 = *(const bf16x8*)(pB0 + k0);
    bf16x8 vb1 = *(const bf16x8*)(pB1 + k0);
    __syncthreads();
    *(bf16x8*)lA0 = va0;
    *(bf16x8*)lA1 = va1;
    *(bf16x8*)lB0 = vb0;
    *(bf16x8*)lB1 = vb1;
    __syncthreads();

    bf16x8 afr[4], bfr[4];
#pragma unroll
    for (int mt = 0; mt < 4; mt++)
      afr[mt] = *(const bf16x8*)&As[(mBase + mt * 16 + fr) * 32 + fq];
#pragma unroll
    for (int nt = 0; nt < 4; nt++)
      bfr[nt] = *(const bf16x8*)&Bs[(nBase + nt * 16 + fr) * 32 + fq];

#pragma unroll
    for (int mt = 0; mt < 4; mt++)
#pragma unroll
      for (int nt = 0; nt < 4; nt++)
        acc[mt][nt] = __builtin_amdgcn_mfma_f32_16x16x32_bf16(afr[mt], bfr[nt], acc[mt][nt], 0, 0, 0);
  }

  const int orow = (lane >> 4) * 4;
  const int ocol = lane & 15;
#pragma unroll
  for (int mt = 0; mt < 4; mt++) {
#pragma unroll
    for (int nt = 0; nt < 4; nt++) {
      int gr = m0 + mBase + mt * 16 + orow;
      int gc = n0 + nBase + nt * 16 + ocol;
      float bv = BIAS ? bias[gc] : 0.0f;
#pragma unroll
      for (int r = 0; r < 4; r++) {
        float v = acc[mt][nt][r] + bv;
        Cout[(long)(gr + r) * ldc + gc] = (bf16)v;
      }
    }
  }
}

// ---------------------------------------------------------------- converters
__global__ __launch_bounds__(256)
void transpose_conv(const void* __restrict__ in, bf16* __restrict__ out,
                    const int* __restrict__ flag, int R, int C)
{
  __shared__ float tile[32][33];
  int f = *flag;
  int x = blockIdx.x * 32 + threadIdx.x;
  int yb = blockIdx.y * 32;
#pragma unroll
  for (int i = threadIdx.y; i < 32; i += 8) {
    long idx = (long)(yb + i) * C + x;
    tile[i][threadIdx.x] = f ? ((const float*)in)[idx] : (float)((const bf16*)in)[idx];
  }
  __syncthreads();
  int x2 = yb + threadIdx.x;
  int y2b = blockIdx.x * 32;
#pragma unroll
  for (int i = threadIdx.y; i < 32; i += 8)
    out[(long)(y2b + i) * R + x2] = (bf16)tile[threadIdx.x][i];
}

// dual-base transpose+convert: picks f32 or bf16 source per flag
__global__ __launch_bounds__(256)
void transpose_conv2(const void* __restrict__ in32, const void* __restrict__ in16,
                     bf16* __restrict__ out, const int* __restrict__ flag, int R, int C)
{
  __shared__ float tile[32][33];
  int f = *flag;
  int x = blockIdx.x * 32 + threadIdx.x;
  int yb = blockIdx.y * 32;
#pragma unroll
  for (int i = threadIdx.y; i < 32; i += 8) {
    long idx = (long)(yb + i) * C + x;
    tile[i][threadIdx.x] = f ? ((const float*)in32)[idx] : (float)((const bf16*)in16)[idx];
  }
  __syncthreads();
  int x2 = yb + threadIdx.x;
  int y2b = blockIdx.x * 32;
#pragma unroll
  for (int i = threadIdx.y; i < 32; i += 8)
    out[(long)(y2b + i) * R + x2] = (bf16)tile[threadIdx.x][i];
}

__global__ __launch_bounds__(256)
void conv_to_f32(const void* __restrict__ in, float* __restrict__ out,
                 const int* __restrict__ flag, int n)
{
  int i = blockIdx.x * blockDim.x + threadIdx.x;
  if (i >= n) return;
  out[i] = (*flag) ? ((const float*)in)[i] : (float)((const bf16*)in)[i];
}

// ---------------------------------------------------------------- scan
__global__ __launch_bounds__(256)
void scan_pass1(const bf16* __restrict__ HG, float* __restrict__ Ab, float* __restrict__ Pb)
{
  int tid = blockIdx.x * blockDim.x + threadIdx.x;
  int c  = tid & (HIDIM - 1);
  int bj = tid >> 10;
  int j  = bj & (SCAN_C - 1);
  int b  = bj >> 5;
  const bf16* base = HG + ((long)(b * S_LEN + j * SCAN_T)) * 2048 + c;
  float A = 1.0f, P = 0.0f;
#pragma unroll 4
  for (int t = 0; t < SCAN_T; t++) {
    float hid = (float)base[(long)t * 2048];
    float gt  = (float)base[(long)t * 2048 + 1024];
    float a, v; av_calc(hid, gt, a, v);
    A *= a;
    P = fmaf(a, P, v);
  }
  Ab[tid] = A;
  Pb[tid] = P;
}

__global__ __launch_bounds__(256)
void scan_pass2(const float* __restrict__ Ab, float* __restrict__ Pb)
{
  int tid = blockIdx.x * blockDim.x + threadIdx.x;
  int c = tid & (HIDIM - 1);
  int b = tid >> 10;
  float h = 0.0f;
  for (int j = 0; j < SCAN_C; j++) {
    long i = ((long)(b * SCAN_C + j) << 10) + c;
    float A = Ab[i];
    float P = Pb[i];
    Pb[i] = h;
    h = fmaf(A, h, P);
  }
}

__global__ __launch_bounds__(256)
void scan_pass3(bf16* __restrict__ HG, const float* __restrict__ Pb)
{
  int tid = blockIdx.x * blockDim.x + threadIdx.x;
  int c  = tid & (HIDIM - 1);
  int bj = tid >> 10;
  int j  = bj & (SCAN_C - 1);
  int b  = bj >> 5;
  bf16* base = HG + ((long)(b * S_LEN + j * SCAN_T)) * 2048 + c;
  float h = Pb[tid];
#pragma unroll 4
  for (int t = 0; t < SCAN_T; t++) {
    float hid = (float)base[(long)t * 2048];
    float gt  = (float)base[(long)t * 2048 + 1024];
    float a, v; av_calc(hid, gt, a, v);
    h = fmaf(a, h, v);
    base[(long)t * 2048] = (bf16)h;
  }
}

// ---------------------------------------------------------------- shift / output
__global__ __launch_bounds__(256)
void rev_build(const bf16* __restrict__ X, bf16* __restrict__ X2, const int* __restrict__ lens)
{
  int bt = blockIdx.x;
  int b = bt >> 11;
  int t = bt & (S_LEN - 1);
  int pad = S_LEN - lens[b];
  int src = S_LEN - 1 - ((t + pad) & (S_LEN - 1));
  const u32* s = (const u32*)(X + (long)(b * S_LEN + src) * HDIM);
  u32* d = (u32*)(X2 + (long)(b * S_LEN + t) * HDIM);
  d[threadIdx.x] = s[threadIdx.x];
}

__global__ __launch_bounds__(256)
void finalize_out(const bf16* __restrict__ X, const bf16* __restrict__ X2,
                  const int* __restrict__ lens, const int* __restrict__ flag,
                  void* __restrict__ out)
{
  int bt = blockIdx.x;
  int b = bt >> 11;
  int t = bt & (S_LEN - 1);
  int pad = S_LEN - lens[b];
  int src = S_LEN - 1 - ((t + pad) & (S_LEN - 1));
  const bf16* sf = X  + (long)(b * S_LEN + t) * HDIM;
  const bf16* sr = X2 + (long)(b * S_LEN + src) * HDIM;
  long ro = (long)(b * S_LEN + t) * 1024;
  if (*flag) {
    float* d = (float*)out + ro;
    for (int c = threadIdx.x; c < 512; c += 256) {
      d[c]       = (float)sf[c];
      d[512 + c] = (float)sr[c];
    }
  } else {
    bf16* d = (bf16*)out + ro;
    for (int c = threadIdx.x; c < 512; c += 256) {
      d[c]       = sf[c];
      d[512 + c] = sr[c];
    }
  }
}

__global__ __launch_bounds__(256)
void seq_out_k(const bf16* __restrict__ X, const bf16* __restrict__ X2,
               const int* __restrict__ lens, const int* __restrict__ flag,
               void* __restrict__ out)
{
  int b = blockIdx.x;
  int t = lens[b] - 1;
  const bf16* sf = X  + (long)(b * S_LEN + t) * HDIM;
  const bf16* sr = X2 + (long)(b * S_LEN + 0) * HDIM;
  long off = (long)BATCH * S_LEN * 1024 + (long)b * 1024;
  if (*flag) {
    float* d = (float*)out + off;
    for (int c = threadIdx.x; c < 512; c += 256) {
      d[c]       = (float)sf[c];
      d[512 + c] = (float)sr[c];
    }
  } else {
    bf16* d = (bf16*)out + off;
    for (int c = threadIdx.x; c < 512; c += 256) {
      d[c]       = sf[c];
      d[512 + c] = sr[c];
    }
  }
}

// ---------------------------------------------------------------- launch
extern "C" void kernel_launch(void* const* d_in, const int* in_sizes, int n_in,
                              void* d_out, int out_size, void* d_ws, size_t ws_size,
                              hipStream_t stream)
{
  (void)in_sizes; (void)n_in; (void)out_size;
  const int* x_source = (const int*)d_in[0];
  const int* x_len    = (const int*)d_in[1];
  const void* emb     = d_in[2];
  const void* W_er    = d_in[3];
  const void* b_er    = d_in[4];
  const void* W_hg[2]  = { d_in[5], d_in[7] };   // [3,512,2048]
  const void* W_out[2] = { d_in[6], d_in[8] };   // [3,1024,512]

  char* ws = (char*)d_ws;
  size_t off = 0;
  auto alloc = [&](size_t bytes) -> char* {
    char* p = ws + off;
    off += (bytes + 255) & ~(size_t)255;
    return p;
  };
  auto a256 = [](size_t b) -> size_t { return (b + 255) & ~(size_t)255; };

  int*   flag = (int*)  alloc(256);
  float* berF = (float*)alloc(512 * 4);
  bf16*  WerT = (bf16*) alloc((size_t)512 * 512 * 2);
  bf16*  X    = (bf16*) alloc((size_t)BATCH * S_LEN * HDIM * 2);   // fwd acts, 32 MB
  bf16*  X2   = (bf16*) alloc((size_t)BATCH * S_LEN * HDIM * 2);   // rev acts, 32 MB
  bf16* WhgT[2][NLAYER];
  bf16* WoutT[2][NLAYER];
  for (int d = 0; d < 2; d++)
    for (int l = 0; l < NLAYER; l++) {
      WhgT[d][l]  = (bf16*)alloc((size_t)2048 * 512 * 2);
      WoutT[d][l] = (bf16*)alloc((size_t)512 * 1024 * 2);
    }

  size_t fixedEnd = off;
  int bch = 16;
  while (bch > 1) {
    size_t need = fixedEnd
      + a256((size_t)bch * S_LEN * 2048 * 2)
      + 2 * a256((size_t)bch * SCAN_C * HIDIM * 4);
    if (need <= ws_size) break;
    bch >>= 1;
  }
  bf16*  HG = (bf16*) alloc((size_t)bch * S_LEN * 2048 * 2);
  float* Ab = (float*)alloc((size_t)bch * SCAN_C * HIDIM * 4);
  float* Pb = (float*)alloc((size_t)bch * SCAN_C * HIDIM * 4);

  probe_dtype<<<1, 64, 0, stream>>>((const unsigned short*)emb, flag);

  conv_to_f32<<<2, 256, 0, stream>>>(b_er, berF, flag, 512);
  dim3 tb(32, 8);
  transpose_conv<<<dim3(16, 16), tb, 0, stream>>>(W_er, WerT, flag, 512, 512);
  for (int d = 0; d < 2; d++)
    for (int l = 0; l < NLAYER; l++) {
      const char* hg32 = (const char*)W_hg[d] + (size_t)l * 512 * 2048 * 4;
      const char* hg16 = (const char*)W_hg[d] + (size_t)l * 512 * 2048 * 2;
      const char* wo32 = (const char*)W_out[d] + (size_t)l * 1024 * 512 * 4;
      const char* wo16 = (const char*)W_out[d] + (size_t)l * 1024 * 512 * 2;
      transpose_conv2<<<dim3(2048 / 32, 512 / 32), tb, 0, stream>>>(hg32, hg16, WhgT[d][l], flag, 512, 2048);
      transpose_conv2<<<dim3(512 / 32, 1024 / 32), tb, 0, stream>>>(wo32, wo16, WoutT[d][l], flag, 1024, 512);
    }

  // x_emb = emb[x_source] @ W_er + b_er -> X (bf16)   (gather path, dtype via flag)
  gemm_mfma<1, 1><<<dim3(4, (BATCH * S_LEN) / 128), 256, 0, stream>>>(
      emb, WerT, X, berF, x_source, flag, BATCH * S_LEN, 512, 512, 512, 512);

  rev_build<<<BATCH * S_LEN, 256, 0, stream>>>(X, X2, x_len);

  for (int d = 0; d < 2; d++) {
    bf16* Xd = d ? X2 : X;
    for (int l = 0; l < NLAYER; l++) {
      for (int cb = 0; cb < BATCH / bch; cb++) {
        bf16* Ain = Xd + (size_t)cb * bch * S_LEN * HDIM;
        int Mrows = bch * S_LEN;
        // HG = Ain @ W_hg   [Mrows,512] x [512,2048]
        gemm8<<<dim3(2048 / 256, Mrows / 256), 512, 131072, stream>>>(
            Ain, WhgT[d][l], HG, 512, 512, 2048);
        int nthr = bch * SCAN_C * HIDIM;
        scan_pass1<<<nthr / 256, 256, 0, stream>>>(HG, Ab, Pb);
        scan_pass2<<<(bch * HIDIM) / 256, 256, 0, stream>>>(Ab, Pb);
        scan_pass3<<<nthr / 256, 256, 0, stream>>>(HG, Pb);
        // Ain = h @ W_out   [Mrows,1024(stride 2048)] x [1024,512]
        gemm8<<<dim3(512 / 256, Mrows / 256), 512, 131072, stream>>>(
            HG, WoutT[d][l], Ain, 1024, 2048, 512);
      }
    }
  }

  finalize_out<<<BATCH * S_LEN, 256, 0, stream>>>(X, X2, x_len, flag, d_out);
  seq_out_k<<<BATCH, 256, 0, stream>>>(X, X2, x_len, flag, d_out);
}

// Round 4
// 1756.350 us; speedup vs baseline: 1.0212x; 1.0118x over previous
//
#include <hip/hip_runtime.h>
#include <hip/hip_bf16.h>
#include <stdint.h>

#define S_LEN  2048
#define BATCH  16
#define HDIM   512
#define HIDIM  1024
#define NLAYER 3
#define SCAN_C 32
#define SCAN_T 64

typedef __hip_bfloat16 bf16;
typedef __attribute__((ext_vector_type(8))) short bf16x8;
typedef __attribute__((ext_vector_type(4))) float f32x4;
typedef unsigned int u32;

// direct global->LDS, 16B per lane; LDS dest is wave-uniform base + lane*16
#define GLOAD16(gp, lp) __builtin_amdgcn_global_load_lds(                 \
    (const __attribute__((address_space(1))) void*)(gp),                  \
    (__attribute__((address_space(3))) void*)(lp), 16, 0, 0)

#define FENCE asm volatile("" ::: "memory")
#define BAR   do { FENCE; __builtin_amdgcn_s_barrier(); FENCE; } while (0)
#define VMCNT(n) asm volatile("s_waitcnt vmcnt(" #n ")" ::: "memory")

// ---------------------------------------------------------------- dtype probe
// flag=1: float buffers are f32; flag=0: bf16.
__global__ void probe_dtype(const unsigned short* __restrict__ w, int* __restrict__ flag)
{
  int cnt = 0;
  for (int i = threadIdx.x; i < 4096; i += 64) {
    unsigned short m = w[i] & 0x7FFF;
    if (m > 0x4080) cnt++;              // |x| > 4.0 (or inf/nan), integer compare
  }
  for (int o = 32; o; o >>= 1) cnt += __shfl_down(cnt, o, 64);
  if (threadIdx.x == 0) *flag = (cnt > 64) ? 1 : 0;
}

// ---------------------------------------------------------------- activation
__device__ __forceinline__ void av_calc(float hid, float gate, float& a, float& v) {
  a = 1.0f / (1.0f + __expf(gate));
  float z = 1.0f / (1.0f + __expf(-gate));
  float g = (hid >= 0.0f) ? (hid + 0.5f) : (1.0f / (1.0f + __expf(-hid)));
  v = z * g;
}

__device__ __forceinline__ short f2bs(float f) {
  bf16 h = (bf16)f;
  return *(short*)&h;
}

__device__ __forceinline__ bf16x8 pack8(float4 a, float4 b) {
  bf16x8 r;
  r[0] = f2bs(a.x); r[1] = f2bs(a.y); r[2] = f2bs(a.z); r[3] = f2bs(a.w);
  r[4] = f2bs(b.x); r[5] = f2bs(b.y); r[6] = f2bs(b.z); r[7] = f2bs(b.w);
  return r;
}

// ================================================================ 8-phase 256^2 GEMM
// C[M,N] = A[M,K] * Bt[N,K]^T ; bf16. M,N mult of 256; K mult of 128.
// Dual-base: rows >= mHalf switch to {Aa2,Bt2,Ca2} (fwd/rev dir batching).
// T2 swizzle: LDS holds logical (row, colbyte^((row&7)<<4)); global SOURCE is
// inverse-swizzled (global_load_lds dest must stay linear); ds_read XORs back.

__device__ __forceinline__ void stage_half(const bf16* __restrict__ G, int row0, int ld,
                                           int kbase, char* lhalf, int tid)
{
  // 128 rows x 64 cols, 2 gloads/thread (64 rows each)
  const int r  = tid >> 3;                                   // 0..63
  const int cc = (((tid & 7) ^ ((tid >> 3) & 7)) << 3);      // swizzled col chunk (elems)
  const bf16* g0 = G + (long)(row0 + r) * ld + (kbase + cc);
  char* l = lhalf + ((tid >> 6) << 10);                      // wave-uniform base
  GLOAD16(g0, l);
  GLOAD16(g0 + (long)64 * ld, l + 8192);
}

__device__ __forceinline__ bf16x8 frag_ld(const char* base, int Rl, int cb) {
  return *(const bf16x8*)(base + Rl * 128 + (cb ^ ((Rl & 7) << 4)));
}

__global__ __launch_bounds__(512, 2)
void gemm8(const bf16* __restrict__ Aa, const bf16* __restrict__ Aa2,
           const bf16* __restrict__ Bta, const bf16* __restrict__ Bta2,
           bf16* __restrict__ Ca, bf16* __restrict__ Ca2,
           int K, int lda, int ldc, int mHalf)
{
  extern __shared__ char lds[];          // 128 KiB: buf0{A,B} buf1{A,B}

  const int tid  = threadIdx.x;
  const int wave = tid >> 6;
  const int lane = tid & 63;
  const int wm = wave >> 2;              // 0..1  (row half)
  const int wn = wave & 3;               // 0..3  (col quarter)

  // bijective XCD swizzle (nwg % 8 == 0 at all our shapes)
  const u32 nwg = gridDim.x * gridDim.y;
  const u32 hb  = blockIdx.y * gridDim.x + blockIdx.x;
  const u32 cpx = nwg >> 3;
  const u32 swz = (hb & 7u) * cpx + (hb >> 3);
  const int m0g = (int)(swz / gridDim.x) * 256;
  const int n0  = (int)(swz % gridDim.x) * 256;

  // dir split (uniform per block)
  const bf16* A  = (m0g >= mHalf) ? Aa2 : Aa;
  const bf16* Bt = (m0g >= mHalf) ? Bta2 : Bta;
  bf16*       Cout = (m0g >= mHalf) ? Ca2 : Ca;
  const int m0 = (m0g >= mHalf) ? (m0g - mHalf) : m0g;

  char* A0 = lds;                        // buf0 A 32K
  char* B0 = lds + 32768;                // buf0 B 32K
  char* A1 = lds + 65536;                // buf1 A 32K
  char* B1 = lds + 98304;                // buf1 B 32K

  const int fr = lane & 15;
  const int qh = lane >> 4;              // 0..3
  const int cqh = qh * 16;               // colbyte base of this lane's k-chunk

  f32x4 acc[8][4];
#pragma unroll
  for (int i = 0; i < 8; i++)
#pragma unroll
    for (int j = 0; j < 4; j++)
#pragma unroll
      for (int r = 0; r < 4; r++) acc[i][j][r] = 0.0f;

  const int NJ = K >> 7;                 // K / 128 (2 BK=64 tiles per iter)

  // ---- prologue: tile0 full -> buf0 ; tile1 B halves -> buf1 (12 loads/thread)
  stage_half(A,  m0,       lda, 0,  A0,         tid);
  stage_half(A,  m0 + 128, lda, 0,  A0 + 16384, tid);
  stage_half(Bt, n0,       K,   0,  B0,         tid);
  stage_half(Bt, n0 + 128, K,   0,  B0 + 16384, tid);
  stage_half(Bt, n0,       K,   64, B1,         tid);
  stage_half(Bt, n0 + 128, K,   64, B1 + 16384, tid);
  VMCNT(4);                              // tile0 landed; tile1-B stays in flight
  BAR;

  for (int j = 0; j < NJ; ++j) {
    const int last = (j == NJ - 1);
    const int kO  = (2 * j + 1) * 64;    // odd tile kbase (always valid)
    const int kE2 = (2 * j + 2) * 64;    // next even tile kbase
    const int kO2 = (2 * j + 3) * 64;    // next odd tile kbase

    // ======== even tile (buf0): phases 1-4 ========
    {
      bf16x8 bfrag[4][2];
#pragma unroll
      for (int q = 0; q < 4; ++q) {
        if (q == 0) {
#pragma unroll
          for (int nt = 0; nt < 4; ++nt)
#pragma unroll
            for (int kk = 0; kk < 2; ++kk)
              bfrag[nt][kk] = frag_ld(B0, wn * 64 + nt * 16 + fr, kk * 64 + cqh);
        }
        bf16x8 afrag[2][2];
#pragma unroll
        for (int t = 0; t < 2; ++t)
#pragma unroll
          for (int kk = 0; kk < 2; ++kk)
            afrag[t][kk] = frag_ld(A0, wm * 128 + (2 * q + t) * 16 + fr, kk * 64 + cqh);

        // staging plan: ph1 = odd-tile A (4), ph2/ph3 = next-even B halves
        if (q == 0) {
          stage_half(A, m0,       lda, kO, A1,         tid);
          stage_half(A, m0 + 128, lda, kO, A1 + 16384, tid);
        } else if (q == 1) {
          if (!last) stage_half(Bt, n0,       K, kE2, B0,         tid);
        } else if (q == 2) {
          if (!last) stage_half(Bt, n0 + 128, K, kE2, B0 + 16384, tid);
        }

        BAR;
        __builtin_amdgcn_s_setprio(1);
        // kk OUTER: 8 independent MFMAs between dependent pairs on the same acc
#pragma unroll
        for (int kk = 0; kk < 2; ++kk)
#pragma unroll
          for (int nt = 0; nt < 4; ++nt)
#pragma unroll
            for (int t = 0; t < 2; ++t)
              acc[2 * q + t][nt] = __builtin_amdgcn_mfma_f32_16x16x32_bf16(
                  afrag[t][kk], bfrag[nt][kk], acc[2 * q + t][nt], 0, 0, 0);
        __builtin_amdgcn_s_setprio(0);
        if (q == 3) {                    // phase 4: odd tile must be fully landed
          if (last) { VMCNT(0); } else { VMCNT(4); }
        }
        BAR;
      }
    }

    // ======== odd tile (buf1): phases 5-8 ========
    {
      bf16x8 bfrag[4][2];
#pragma unroll
      for (int q = 0; q < 4; ++q) {
        if (q == 0) {
#pragma unroll
          for (int nt = 0; nt < 4; ++nt)
#pragma unroll
            for (int kk = 0; kk < 2; ++kk)
              bfrag[nt][kk] = frag_ld(B1, wn * 64 + nt * 16 + fr, kk * 64 + cqh);
        }
        bf16x8 afrag[2][2];
#pragma unroll
        for (int t = 0; t < 2; ++t)
#pragma unroll
          for (int kk = 0; kk < 2; ++kk)
            afrag[t][kk] = frag_ld(A1, wm * 128 + (2 * q + t) * 16 + fr, kk * 64 + cqh);

        // staging plan: ph5/ph6 = next-even A halves, ph7/ph8 = next-odd B halves
        if (!last) {
          if (q == 0)      stage_half(A,  m0,       lda, kE2, A0,         tid);
          else if (q == 1) stage_half(A,  m0 + 128, lda, kE2, A0 + 16384, tid);
          else if (q == 2) stage_half(Bt, n0,       K,   kO2, B1,         tid);
          else             stage_half(Bt, n0 + 128, K,   kO2, B1 + 16384, tid);
        }

        BAR;
        __builtin_amdgcn_s_setprio(1);
#pragma unroll
        for (int kk = 0; kk < 2; ++kk)
#pragma unroll
          for (int nt = 0; nt < 4; ++nt)
#pragma unroll
            for (int t = 0; t < 2; ++t)
              acc[2 * q + t][nt] = __builtin_amdgcn_mfma_f32_16x16x32_bf16(
                  afrag[t][kk], bfrag[nt][kk], acc[2 * q + t][nt], 0, 0, 0);
        __builtin_amdgcn_s_setprio(0);
        if (q == 3 && !last) { VMCNT(4); }   // next even tile fully landed
        BAR;
      }
    }
  }

  // epilogue: C/D layout col = lane&15, row = (lane>>4)*4 + reg
  const int orow = qh * 4;
#pragma unroll
  for (int mt = 0; mt < 8; ++mt) {
#pragma unroll
    for (int nt = 0; nt < 4; ++nt) {
      int gr = m0 + wm * 128 + mt * 16 + orow;
      int gc = n0 + wn * 64 + nt * 16 + fr;
#pragma unroll
      for (int r = 0; r < 4; ++r)
        Cout[(long)(gr + r) * ldc + gc] = (bf16)acc[mt][nt][r];
    }
  }
}

// ---------------------------------------------------------------- gather GEMM (embedding)
// C[M,N] = A[gidx[m],K] * Bt[N,K]^T + bias; A dtype per *flag (f32 or bf16).
template<int GATHER, int BIAS>
__global__ __launch_bounds__(256, 2)
void gemm_mfma(const void* __restrict__ Av, const bf16* __restrict__ Bt,
               bf16* __restrict__ Cout, const float* __restrict__ bias,
               const int* __restrict__ gidx, const int* __restrict__ flag,
               int M, int N, int K, int lda, int ldc)
{
  __shared__ bf16 As[128 * 32];
  __shared__ bf16 Bs[128 * 32];

  const int tid  = threadIdx.x;
  const int wave = tid >> 6;
  const int lane = tid & 63;
  const int m0 = blockIdx.y * 128;
  const int n0 = blockIdx.x * 128;

  const int seg0 = wave * 2, seg1 = seg0 + 1;
  const int lr = lane >> 2;
  const int ck = (lane & 3) * 8;
  const int rA0 = seg0 * 16 + lr;
  const int rA1 = seg1 * 16 + lr;

  const int af = GATHER ? *flag : 0;

  long ga0 = GATHER ? (long)gidx[m0 + rA0] : (long)(m0 + rA0);
  long ga1 = GATHER ? (long)gidx[m0 + rA1] : (long)(m0 + rA1);
  const bf16*  hA0 = (const bf16*)Av + ga0 * (long)lda + ck;
  const bf16*  hA1 = (const bf16*)Av + ga1 * (long)lda + ck;
  const float* qA0 = (const float*)Av + ga0 * (long)lda + ck;
  const float* qA1 = (const float*)Av + ga1 * (long)lda + ck;
  const bf16*  pB0 = Bt + (long)(n0 + rA0) * K + ck;
  const bf16*  pB1 = Bt + (long)(n0 + rA1) * K + ck;

  bf16* lA0 = &As[seg0 * 512 + lane * 8];
  bf16* lA1 = &As[seg1 * 512 + lane * 8];
  bf16* lB0 = &Bs[seg0 * 512 + lane * 8];
  bf16* lB1 = &Bs[seg1 * 512 + lane * 8];

  f32x4 acc[4][4];
#pragma unroll
  for (int i = 0; i < 4; i++)
#pragma unroll
    for (int j = 0; j < 4; j++)
#pragma unroll
      for (int r = 0; r < 4; r++) acc[i][j][r] = 0.0f;

  const int mBase = (wave >> 1) * 64;
  const int nBase = (wave & 1) * 64;
  const int fr = lane & 15;
  const int fq = (lane >> 4) * 8;

  for (int k0 = 0; k0 < K; k0 += 32) {
    bf16x8 va0, va1;
    if (GATHER && af) {
      float4 a0 = *(const float4*)(qA0 + k0);
      float4 a1 = *(const float4*)(qA0 + k0 + 4);
      float4 b0 = *(const float4*)(qA1 + k0);
      float4 b1 = *(const float4*)(qA1 + k0 + 4);
      va0 = pack8(a0, a1);
      va1 = pack8(b0, b1);
    } else {
      va0 = *(const bf16x8*)(hA0 + k0);
      va1 = *(const bf16x8*)(hA1 + k0);
    }
    bf16x8 vb0 = *(const bf16x8*)(pB0 + k0);
    bf16x8 vb1 = *(const bf16x8*)(pB1 + k0);
    __syncthreads();
    *(bf16x8*)lA0 = va0;
    *(bf16x8*)lA1 = va1;
    *(bf16x8*)lB0 = vb0;
    *(bf16x8*)lB1 = vb1;
    __syncthreads();

    bf16x8 afr[4], bfr[4];
#pragma unroll
    for (int mt = 0; mt < 4; mt++)
      afr[mt] = *(const bf16x8*)&As[(mBase + mt * 16 + fr) * 32 + fq];
#pragma unroll
    for (int nt = 0; nt < 4; nt++)
      bfr[nt] = *(const bf16x8*)&Bs[(nBase + nt * 16 + fr) * 32 + fq];

#pragma unroll
    for (int mt = 0; mt < 4; mt++)
#pragma unroll
      for (int nt = 0; nt < 4; nt++)
        acc[mt][nt] = __builtin_amdgcn_mfma_f32_16x16x32_bf16(afr[mt], bfr[nt], acc[mt][nt], 0, 0, 0);
  }

  const int orow = (lane >> 4) * 4;
  const int ocol = lane & 15;
#pragma unroll
  for (int mt = 0; mt < 4; mt++) {
#pragma unroll
    for (int nt = 0; nt < 4; nt++) {
      int gr = m0 + mBase + mt * 16 + orow;
      int gc = n0 + nBase + nt * 16 + ocol;
      float bv = BIAS ? bias[gc] : 0.0f;
#pragma unroll
      for (int r = 0; r < 4; r++) {
        float v = acc[mt][nt][r] + bv;
        Cout[(long)(gr + r) * ldc + gc] = (bf16)v;
      }
    }
  }
}

// ---------------------------------------------------------------- converters
__global__ __launch_bounds__(256)
void transpose_conv(const void* __restrict__ in, bf16* __restrict__ out,
                    const int* __restrict__ flag, int R, int C)
{
  __shared__ float tile[32][33];
  int f = *flag;
  int x = blockIdx.x * 32 + threadIdx.x;
  int yb = blockIdx.y * 32;
#pragma unroll
  for (int i = threadIdx.y; i < 32; i += 8) {
    long idx = (long)(yb + i) * C + x;
    tile[i][threadIdx.x] = f ? ((const float*)in)[idx] : (float)((const bf16*)in)[idx];
  }
  __syncthreads();
  int x2 = yb + threadIdx.x;
  int y2b = blockIdx.x * 32;
#pragma unroll
  for (int i = threadIdx.y; i < 32; i += 8)
    out[(long)(y2b + i) * R + x2] = (bf16)tile[threadIdx.x][i];
}

// dual-base transpose+convert: picks f32 or bf16 source per flag
__global__ __launch_bounds__(256)
void transpose_conv2(const void* __restrict__ in32, const void* __restrict__ in16,
                     bf16* __restrict__ out, const int* __restrict__ flag, int R, int C)
{
  __shared__ float tile[32][33];
  int f = *flag;
  int x = blockIdx.x * 32 + threadIdx.x;
  int yb = blockIdx.y * 32;
#pragma unroll
  for (int i = threadIdx.y; i < 32; i += 8) {
    long idx = (long)(yb + i) * C + x;
    tile[i][threadIdx.x] = f ? ((const float*)in32)[idx] : (float)((const bf16*)in16)[idx];
  }
  __syncthreads();
  int x2 = yb + threadIdx.x;
  int y2b = blockIdx.x * 32;
#pragma unroll
  for (int i = threadIdx.y; i < 32; i += 8)
    out[(long)(y2b + i) * R + x2] = (bf16)tile[threadIdx.x][i];
}

__global__ __launch_bounds__(256)
void conv_to_f32(const void* __restrict__ in, float* __restrict__ out,
                 const int* __restrict__ flag, int n)
{
  int i = blockIdx.x * blockDim.x + threadIdx.x;
  if (i >= n) return;
  out[i] = (*flag) ? ((const float*)in)[i] : (float)((const bf16*)in)[i];
}

// ---------------------------------------------------------------- scan
// HG: bf16 [nseq*S_LEN, 2048]; cols 0..1023 hidden, 1024..2047 gate.
__global__ __launch_bounds__(256)
void scan_pass1(const bf16* __restrict__ HG, float* __restrict__ Ab, float* __restrict__ Pb)
{
  int tid = blockIdx.x * blockDim.x + threadIdx.x;
  int c  = tid & (HIDIM - 1);
  int bj = tid >> 10;
  int j  = bj & (SCAN_C - 1);
  int b  = bj >> 5;
  const bf16* base = HG + ((long)(b * S_LEN + j * SCAN_T)) * 2048 + c;
  float A = 1.0f, P = 0.0f;
#pragma unroll 4
  for (int t = 0; t < SCAN_T; t++) {
    float hid = (float)base[(long)t * 2048];
    float gt  = (float)base[(long)t * 2048 + 1024];
    float a, v; av_calc(hid, gt, a, v);
    A *= a;
    P = fmaf(a, P, v);
  }
  Ab[tid] = A;
  Pb[tid] = P;
}

__global__ __launch_bounds__(256)
void scan_pass2(const float* __restrict__ Ab, float* __restrict__ Pb)
{
  int tid = blockIdx.x * blockDim.x + threadIdx.x;
  int c = tid & (HIDIM - 1);
  int b = tid >> 10;
  float h = 0.0f;
  for (int j = 0; j < SCAN_C; j++) {
    long i = ((long)(b * SCAN_C + j) << 10) + c;
    float A = Ab[i];
    float P = Pb[i];
    Pb[i] = h;
    h = fmaf(A, h, P);
  }
}

__global__ __launch_bounds__(256)
void scan_pass3(bf16* __restrict__ HG, const float* __restrict__ Pb)
{
  int tid = blockIdx.x * blockDim.x + threadIdx.x;
  int c  = tid & (HIDIM - 1);
  int bj = tid >> 10;
  int j  = bj & (SCAN_C - 1);
  int b  = bj >> 5;
  bf16* base = HG + ((long)(b * S_LEN + j * SCAN_T)) * 2048 + c;
  float h = Pb[tid];
#pragma unroll 4
  for (int t = 0; t < SCAN_T; t++) {
    float hid = (float)base[(long)t * 2048];
    float gt  = (float)base[(long)t * 2048 + 1024];
    float a, v; av_calc(hid, gt, a, v);
    h = fmaf(a, h, v);
    base[(long)t * 2048] = (bf16)h;
  }
}

// ---------------------------------------------------------------- shift / output
__global__ __launch_bounds__(256)
void rev_build(const bf16* __restrict__ X, bf16* __restrict__ X2, const int* __restrict__ lens)
{
  int bt = blockIdx.x;
  int b = bt >> 11;
  int t = bt & (S_LEN - 1);
  int pad = S_LEN - lens[b];
  int src = S_LEN - 1 - ((t + pad) & (S_LEN - 1));
  const u32* s = (const u32*)(X + (long)(b * S_LEN + src) * HDIM);
  u32* d = (u32*)(X2 + (long)(b * S_LEN + t) * HDIM);
  d[threadIdx.x] = s[threadIdx.x];
}

__global__ __launch_bounds__(256)
void finalize_out(const bf16* __restrict__ X, const bf16* __restrict__ X2,
                  const int* __restrict__ lens, const int* __restrict__ flag,
                  void* __restrict__ out)
{
  int bt = blockIdx.x;
  int b = bt >> 11;
  int t = bt & (S_LEN - 1);
  int pad = S_LEN - lens[b];
  int src = S_LEN - 1 - ((t + pad) & (S_LEN - 1));
  const bf16* sf = X  + (long)(b * S_LEN + t) * HDIM;
  const bf16* sr = X2 + (long)(b * S_LEN + src) * HDIM;
  long ro = (long)(b * S_LEN + t) * 1024;
  if (*flag) {
    float* d = (float*)out + ro;
    for (int c = threadIdx.x; c < 512; c += 256) {
      d[c]       = (float)sf[c];
      d[512 + c] = (float)sr[c];
    }
  } else {
    bf16* d = (bf16*)out + ro;
    for (int c = threadIdx.x; c < 512; c += 256) {
      d[c]       = sf[c];
      d[512 + c] = sr[c];
    }
  }
}

__global__ __launch_bounds__(256)
void seq_out_k(const bf16* __restrict__ X, const bf16* __restrict__ X2,
               const int* __restrict__ lens, const int* __restrict__ flag,
               void* __restrict__ out)
{
  int b = blockIdx.x;
  int t = lens[b] - 1;
  const bf16* sf = X  + (long)(b * S_LEN + t) * HDIM;
  const bf16* sr = X2 + (long)(b * S_LEN + 0) * HDIM;
  long off = (long)BATCH * S_LEN * 1024 + (long)b * 1024;
  if (*flag) {
    float* d = (float*)out + off;
    for (int c = threadIdx.x; c < 512; c += 256) {
      d[c]       = (float)sf[c];
      d[512 + c] = (float)sr[c];
    }
  } else {
    bf16* d = (bf16*)out + off;
    for (int c = threadIdx.x; c < 512; c += 256) {
      d[c]       = sf[c];
      d[512 + c] = sr[c];
    }
  }
}

// ---------------------------------------------------------------- launch
extern "C" void kernel_launch(void* const* d_in, const int* in_sizes, int n_in,
                              void* d_out, int out_size, void* d_ws, size_t ws_size,
                              hipStream_t stream)
{
  (void)in_sizes; (void)n_in; (void)out_size;
  const int* x_source = (const int*)d_in[0];
  const int* x_len    = (const int*)d_in[1];
  const void* emb     = d_in[2];
  const void* W_er    = d_in[3];
  const void* b_er    = d_in[4];
  const void* W_hg[2]  = { d_in[5], d_in[7] };   // [3,512,2048]
  const void* W_out[2] = { d_in[6], d_in[8] };   // [3,1024,512]

  char* ws = (char*)d_ws;
  size_t off = 0;
  auto alloc = [&](size_t bytes) -> char* {
    char* p = ws + off;
    off += (bytes + 255) & ~(size_t)255;
    return p;
  };
  auto a256 = [](size_t b) -> size_t { return (b + 255) & ~(size_t)255; };

  int*   flag = (int*)  alloc(256);
  float* berF = (float*)alloc(512 * 4);
  bf16*  WerT = (bf16*) alloc((size_t)512 * 512 * 2);
  bf16*  X    = (bf16*) alloc((size_t)BATCH * S_LEN * HDIM * 2);   // fwd acts, 32 MB
  bf16*  X2   = (bf16*) alloc((size_t)BATCH * S_LEN * HDIM * 2);   // rev acts, 32 MB
  bf16* WhgT[2][NLAYER];
  bf16* WoutT[2][NLAYER];
  for (int d = 0; d < 2; d++)
    for (int l = 0; l < NLAYER; l++) {
      WhgT[d][l]  = (bf16*)alloc((size_t)2048 * 512 * 2);
      WoutT[d][l] = (bf16*)alloc((size_t)512 * 1024 * 2);
    }

  // virtual dir-seq space: 32 sequences (dir0 = seqs 0..15 in X, dir1 = 16..31 in X2).
  // chunk of bchv dir-seqs processed per GEMM/scan round; bchv=32 fuses both dirs.
  size_t fixedEnd = off;
  int bchv = 32;
  while (bchv > 1) {
    size_t need = fixedEnd
      + a256((size_t)bchv * S_LEN * 2048 * 2)
      + 2 * a256((size_t)bchv * SCAN_C * HIDIM * 4);
    if (need <= ws_size) break;
    bchv >>= 1;
  }
  bf16*  HG = (bf16*) alloc((size_t)bchv * S_LEN * 2048 * 2);
  float* Ab = (float*)alloc((size_t)bchv * SCAN_C * HIDIM * 4);
  float* Pb = (float*)alloc((size_t)bchv * SCAN_C * HIDIM * 4);

  probe_dtype<<<1, 64, 0, stream>>>((const unsigned short*)emb, flag);

  conv_to_f32<<<2, 256, 0, stream>>>(b_er, berF, flag, 512);
  dim3 tb(32, 8);
  transpose_conv<<<dim3(16, 16), tb, 0, stream>>>(W_er, WerT, flag, 512, 512);
  for (int d = 0; d < 2; d++)
    for (int l = 0; l < NLAYER; l++) {
      const char* hg32 = (const char*)W_hg[d] + (size_t)l * 512 * 2048 * 4;
      const char* hg16 = (const char*)W_hg[d] + (size_t)l * 512 * 2048 * 2;
      const char* wo32 = (const char*)W_out[d] + (size_t)l * 1024 * 512 * 4;
      const char* wo16 = (const char*)W_out[d] + (size_t)l * 1024 * 512 * 2;
      transpose_conv2<<<dim3(2048 / 32, 512 / 32), tb, 0, stream>>>(hg32, hg16, WhgT[d][l], flag, 512, 2048);
      transpose_conv2<<<dim3(512 / 32, 1024 / 32), tb, 0, stream>>>(wo32, wo16, WoutT[d][l], flag, 1024, 512);
    }

  // x_emb = emb[x_source] @ W_er + b_er -> X (bf16)   (gather path, dtype via flag)
  gemm_mfma<1, 1><<<dim3(4, (BATCH * S_LEN) / 128), 256, 0, stream>>>(
      emb, WerT, X, berF, x_source, flag, BATCH * S_LEN, 512, 512, 512, 512);

  rev_build<<<BATCH * S_LEN, 256, 0, stream>>>(X, X2, x_len);

  const int nchunk = 32 / bchv;
  for (int l = 0; l < NLAYER; l++) {
    for (int cb = 0; cb < nchunk; cb++) {
      const int s0    = cb * bchv;          // first dir-seq of chunk
      const int Mrows = bchv * S_LEN;
      // chunk straddles dirs only when bchv==32 (split at row 16*S_LEN)
      int mHalf;
      bf16 *Xa, *Xa2; const bf16 *Bh, *Bh2, *Bo, *Bo2;
      if (bchv == 32) {
        mHalf = 16 * S_LEN;
        Xa  = X;  Xa2 = X2;
        Bh  = WhgT[0][l];  Bh2 = WhgT[1][l];
        Bo  = WoutT[0][l]; Bo2 = WoutT[1][l];
      } else {
        const int dir = s0 >> 4;            // chunk entirely within one dir
        mHalf = Mrows;                      // never splits
        Xa  = (dir ? X2 : X) + (size_t)(s0 & 15) * S_LEN * HDIM;
        Xa2 = Xa;
        Bh  = WhgT[dir][l];  Bh2 = Bh;
        Bo  = WoutT[dir][l]; Bo2 = Bo;
      }
      // HG = Xa @ W_hg   [Mrows,512] x [512,2048]
      gemm8<<<dim3(2048 / 256, Mrows / 256), 512, 131072, stream>>>(
          Xa, Xa2, Bh, Bh2, HG, HG + (size_t)mHalf * 2048, 512, 512, 2048, mHalf);
      int nthr = bchv * SCAN_C * HIDIM;
      scan_pass1<<<nthr / 256, 256, 0, stream>>>(HG, Ab, Pb);
      scan_pass2<<<(bchv * HIDIM) / 256, 256, 0, stream>>>(Ab, Pb);
      scan_pass3<<<nthr / 256, 256, 0, stream>>>(HG, Pb);
      // Xa = h @ W_out   [Mrows,1024(stride 2048)] x [1024,512]
      gemm8<<<dim3(512 / 256, Mrows / 256), 512, 131072, stream>>>(
          HG, HG + (size_t)mHalf * 2048, Bo, Bo2, Xa, Xa2, 1024, 2048, 512, mHalf);
    }
  }

  finalize_out<<<BATCH * S_LEN, 256, 0, stream>>>(X, X2, x_len, flag, d_out);
  seq_out_k<<<BATCH, 256, 0, stream>>>(X, X2, x_len, flag, d_out);
}

// Round 5
// 1745.812 us; speedup vs baseline: 1.0273x; 1.0060x over previous
//
#include <hip/hip_runtime.h>
#include <hip/hip_bf16.h>
#include <stdint.h>

#define S_LEN  2048
#define BATCH  16
#define HDIM   512
#define HIDIM  1024
#define NLAYER 3
#define SCAN_C 32
#define SCAN_T 64

typedef __hip_bfloat16 bf16;
typedef __attribute__((ext_vector_type(8))) short bf16x8;
typedef __attribute__((ext_vector_type(4))) float f32x4;
typedef unsigned int u32;

// direct global->LDS, 16B per lane; LDS dest is wave-uniform base + lane*16
#define GLOAD16(gp, lp) __builtin_amdgcn_global_load_lds(                 \
    (const __attribute__((address_space(1))) void*)(gp),                  \
    (__attribute__((address_space(3))) void*)(lp), 16, 0, 0)

#define FENCE asm volatile("" ::: "memory")
#define BAR   do { FENCE; __builtin_amdgcn_s_barrier(); FENCE; } while (0)
#define VMCNT(n) asm volatile("s_waitcnt vmcnt(" #n ")" ::: "memory")

// ---------------------------------------------------------------- dtype probe
// flag=1: float buffers are f32; flag=0: bf16.
__global__ void probe_dtype(const unsigned short* __restrict__ w, int* __restrict__ flag)
{
  int cnt = 0;
  for (int i = threadIdx.x; i < 4096; i += 64) {
    unsigned short m = w[i] & 0x7FFF;
    if (m > 0x4080) cnt++;              // |x| > 4.0 (or inf/nan), integer compare
  }
  for (int o = 32; o; o >>= 1) cnt += __shfl_down(cnt, o, 64);
  if (threadIdx.x == 0) *flag = (cnt > 64) ? 1 : 0;
}

// ---------------------------------------------------------------- activation
__device__ __forceinline__ void av_calc(float hid, float gate, float& a, float& v) {
  a = 1.0f / (1.0f + __expf(gate));
  float z = 1.0f / (1.0f + __expf(-gate));
  float g = (hid >= 0.0f) ? (hid + 0.5f) : (1.0f / (1.0f + __expf(-hid)));
  v = z * g;
}

__device__ __forceinline__ short f2bs(float f) {
  bf16 h = (bf16)f;
  return *(short*)&h;
}

__device__ __forceinline__ float bs2f(unsigned short s) {
  bf16 h;
  *(unsigned short*)&h = s;
  return (float)h;
}

__device__ __forceinline__ bf16x8 pack8(float4 a, float4 b) {
  bf16x8 r;
  r[0] = f2bs(a.x); r[1] = f2bs(a.y); r[2] = f2bs(a.z); r[3] = f2bs(a.w);
  r[4] = f2bs(b.x); r[5] = f2bs(b.y); r[6] = f2bs(b.z); r[7] = f2bs(b.w);
  return r;
}

// ================================================================ 8-phase 256^2 GEMM
// C[M,N] = A[M,K] * Bt[N,K]^T ; bf16. M,N mult of 256; K mult of 128.
// Dual-base: rows >= mHalf switch to {Aa2,Bt2,Ca2} (fwd/rev dir batching).
// T2 swizzle: LDS holds logical (row, colbyte^((row&7)<<4)); global SOURCE is
// inverse-swizzled (global_load_lds dest must stay linear); ds_read XORs back.
// A-fragment ds_reads are pipelined ONE PHASE AHEAD (reg double-buffer) so the
// LDS pipe works while MFMAs issue; hipcc's counted lgkmcnt keeps the next
// phase's reads outstanding across the MFMA cluster (m97 asm evidence).

__device__ __forceinline__ void stage_half(const bf16* __restrict__ G, int row0, int ld,
                                           int kbase, char* lhalf, int tid)
{
  // 128 rows x 64 cols, 2 gloads/thread (64 rows each)
  const int r  = tid >> 3;                                   // 0..63
  const int cc = (((tid & 7) ^ ((tid >> 3) & 7)) << 3);      // swizzled col chunk (elems)
  const bf16* g0 = G + (long)(row0 + r) * ld + (kbase + cc);
  char* l = lhalf + ((tid >> 6) << 10);                      // wave-uniform base
  GLOAD16(g0, l);
  GLOAD16(g0 + (long)64 * ld, l + 8192);
}

__device__ __forceinline__ bf16x8 frag_ld(const char* base, int Rl, int cb) {
  return *(const bf16x8*)(base + Rl * 128 + (cb ^ ((Rl & 7) << 4)));
}

__global__ __launch_bounds__(512, 2)
void gemm8(const bf16* __restrict__ Aa, const bf16* __restrict__ Aa2,
           const bf16* __restrict__ Bta, const bf16* __restrict__ Bta2,
           bf16* __restrict__ Ca, bf16* __restrict__ Ca2,
           int K, int lda, int ldc, int mHalf)
{
  extern __shared__ char lds[];          // 128 KiB: buf0{A,B} buf1{A,B}

  const int tid  = threadIdx.x;
  const int wave = tid >> 6;
  const int lane = tid & 63;
  const int wm = wave >> 2;              // 0..1  (row half)
  const int wn = wave & 3;               // 0..3  (col quarter)

  // bijective XCD swizzle (nwg % 8 == 0 at all our shapes)
  const u32 nwg = gridDim.x * gridDim.y;
  const u32 hb  = blockIdx.y * gridDim.x + blockIdx.x;
  const u32 cpx = nwg >> 3;
  const u32 swz = (hb & 7u) * cpx + (hb >> 3);
  const int m0g = (int)(swz / gridDim.x) * 256;
  const int n0  = (int)(swz % gridDim.x) * 256;

  // dir split (uniform per block)
  const bf16* A  = (m0g >= mHalf) ? Aa2 : Aa;
  const bf16* Bt = (m0g >= mHalf) ? Bta2 : Bta;
  bf16*       Cout = (m0g >= mHalf) ? Ca2 : Ca;
  const int m0 = (m0g >= mHalf) ? (m0g - mHalf) : m0g;

  char* A0 = lds;                        // buf0 A 32K
  char* B0 = lds + 32768;                // buf0 B 32K
  char* A1 = lds + 65536;                // buf1 A 32K
  char* B1 = lds + 98304;                // buf1 B 32K

  const int fr = lane & 15;
  const int qh = lane >> 4;              // 0..3
  const int cqh = qh * 16;               // colbyte base of this lane's k-chunk

  f32x4 acc[8][4];
#pragma unroll
  for (int i = 0; i < 8; i++)
#pragma unroll
    for (int j = 0; j < 4; j++)
#pragma unroll
      for (int r = 0; r < 4; r++) acc[i][j][r] = 0.0f;

  const int NJ = K >> 7;                 // K / 128 (2 BK=64 tiles per iter)

  // ---- prologue: tile0 full -> buf0 ; tile1 B halves -> buf1 (12 loads/thread)
  stage_half(A,  m0,       lda, 0,  A0,         tid);
  stage_half(A,  m0 + 128, lda, 0,  A0 + 16384, tid);
  stage_half(Bt, n0,       K,   0,  B0,         tid);
  stage_half(Bt, n0 + 128, K,   0,  B0 + 16384, tid);
  stage_half(Bt, n0,       K,   64, B1,         tid);
  stage_half(Bt, n0 + 128, K,   64, B1 + 16384, tid);
  VMCNT(4);                              // tile0 landed; tile1-B stays in flight
  BAR;

  for (int j = 0; j < NJ; ++j) {
    const int last = (j == NJ - 1);
    const int kO  = (2 * j + 1) * 64;    // odd tile kbase (always valid)
    const int kE2 = (2 * j + 2) * 64;    // next even tile kbase
    const int kO2 = (2 * j + 3) * 64;    // next odd tile kbase

    // ======== even tile (buf0): phases 1-4 ========
    {
      bf16x8 bfrag[4][2];
      bf16x8 af[2][2][2];                // [phase&1][t][kk]
#pragma unroll
      for (int q = 0; q < 4; ++q) {
        // staging plan: ph1 = odd-tile A (4), ph2/ph3 = next-even B halves
        if (q == 0) {
          stage_half(A, m0,       lda, kO, A1,         tid);
          stage_half(A, m0 + 128, lda, kO, A1 + 16384, tid);
        } else if (q == 1) {
          if (!last) stage_half(Bt, n0,       K, kE2, B0,         tid);
        } else if (q == 2) {
          if (!last) stage_half(Bt, n0 + 128, K, kE2, B0 + 16384, tid);
        }

        if (q == 0) {
          // B-frags (whole tile) + this phase's A-frags
#pragma unroll
          for (int nt = 0; nt < 4; ++nt)
#pragma unroll
            for (int kk = 0; kk < 2; ++kk)
              bfrag[nt][kk] = frag_ld(B0, wn * 64 + nt * 16 + fr, kk * 64 + cqh);
#pragma unroll
          for (int t = 0; t < 2; ++t)
#pragma unroll
            for (int kk = 0; kk < 2; ++kk)
              af[0][t][kk] = frag_ld(A0, wm * 128 + t * 16 + fr, kk * 64 + cqh);
        }
        // pipeline: next phase's A-frags (issued before barrier; MFMA below
        // only waits on its own frags via compiler counted lgkmcnt)
        if (q < 3) {
#pragma unroll
          for (int t = 0; t < 2; ++t)
#pragma unroll
            for (int kk = 0; kk < 2; ++kk)
              af[(q + 1) & 1][t][kk] =
                  frag_ld(A0, wm * 128 + (2 * (q + 1) + t) * 16 + fr, kk * 64 + cqh);
        }

        BAR;
        __builtin_amdgcn_s_setprio(1);
#pragma unroll
        for (int kk = 0; kk < 2; ++kk)
#pragma unroll
          for (int nt = 0; nt < 4; ++nt)
#pragma unroll
            for (int t = 0; t < 2; ++t)
              acc[2 * q + t][nt] = __builtin_amdgcn_mfma_f32_16x16x32_bf16(
                  af[q & 1][t][kk], bfrag[nt][kk], acc[2 * q + t][nt], 0, 0, 0);
        __builtin_amdgcn_s_setprio(0);
        if (q == 3) {                    // phase 4: odd tile must be fully landed
          if (last) { VMCNT(0); } else { VMCNT(4); }
        }
        BAR;
      }
    }

    // ======== odd tile (buf1): phases 5-8 ========
    {
      bf16x8 bfrag[4][2];
      bf16x8 af[2][2][2];
#pragma unroll
      for (int q = 0; q < 4; ++q) {
        // staging plan: ph5/ph6 = next-even A halves, ph7/ph8 = next-odd B halves
        if (!last) {
          if (q == 0)      stage_half(A,  m0,       lda, kE2, A0,         tid);
          else if (q == 1) stage_half(A,  m0 + 128, lda, kE2, A0 + 16384, tid);
          else if (q == 2) stage_half(Bt, n0,       K,   kO2, B1,         tid);
          else             stage_half(Bt, n0 + 128, K,   kO2, B1 + 16384, tid);
        }

        if (q == 0) {
#pragma unroll
          for (int nt = 0; nt < 4; ++nt)
#pragma unroll
            for (int kk = 0; kk < 2; ++kk)
              bfrag[nt][kk] = frag_ld(B1, wn * 64 + nt * 16 + fr, kk * 64 + cqh);
#pragma unroll
          for (int t = 0; t < 2; ++t)
#pragma unroll
            for (int kk = 0; kk < 2; ++kk)
              af[0][t][kk] = frag_ld(A1, wm * 128 + t * 16 + fr, kk * 64 + cqh);
        }
        if (q < 3) {
#pragma unroll
          for (int t = 0; t < 2; ++t)
#pragma unroll
            for (int kk = 0; kk < 2; ++kk)
              af[(q + 1) & 1][t][kk] =
                  frag_ld(A1, wm * 128 + (2 * (q + 1) + t) * 16 + fr, kk * 64 + cqh);
        }

        BAR;
        __builtin_amdgcn_s_setprio(1);
#pragma unroll
        for (int kk = 0; kk < 2; ++kk)
#pragma unroll
          for (int nt = 0; nt < 4; ++nt)
#pragma unroll
            for (int t = 0; t < 2; ++t)
              acc[2 * q + t][nt] = __builtin_amdgcn_mfma_f32_16x16x32_bf16(
                  af[q & 1][t][kk], bfrag[nt][kk], acc[2 * q + t][nt], 0, 0, 0);
        __builtin_amdgcn_s_setprio(0);
        if (q == 3 && !last) { VMCNT(4); }   // next even tile fully landed
        BAR;
      }
    }
  }

  // epilogue: C/D layout col = lane&15, row = (lane>>4)*4 + reg
  const int orow = qh * 4;
#pragma unroll
  for (int mt = 0; mt < 8; ++mt) {
#pragma unroll
    for (int nt = 0; nt < 4; ++nt) {
      int gr = m0 + wm * 128 + mt * 16 + orow;
      int gc = n0 + wn * 64 + nt * 16 + fr;
#pragma unroll
      for (int r = 0; r < 4; ++r)
        Cout[(long)(gr + r) * ldc + gc] = (bf16)acc[mt][nt][r];
    }
  }
}

// ---------------------------------------------------------------- gather GEMM (embedding)
// C[M,N] = A[gidx[m],K] * Bt[N,K]^T + bias; A dtype per *flag (f32 or bf16).
template<int GATHER, int BIAS>
__global__ __launch_bounds__(256, 2)
void gemm_mfma(const void* __restrict__ Av, const bf16* __restrict__ Bt,
               bf16* __restrict__ Cout, const float* __restrict__ bias,
               const int* __restrict__ gidx, const int* __restrict__ flag,
               int M, int N, int K, int lda, int ldc)
{
  __shared__ bf16 As[128 * 32];
  __shared__ bf16 Bs[128 * 32];

  const int tid  = threadIdx.x;
  const int wave = tid >> 6;
  const int lane = tid & 63;
  const int m0 = blockIdx.y * 128;
  const int n0 = blockIdx.x * 128;

  const int seg0 = wave * 2, seg1 = seg0 + 1;
  const int lr = lane >> 2;
  const int ck = (lane & 3) * 8;
  const int rA0 = seg0 * 16 + lr;
  const int rA1 = seg1 * 16 + lr;

  const int af = GATHER ? *flag : 0;

  long ga0 = GATHER ? (long)gidx[m0 + rA0] : (long)(m0 + rA0);
  long ga1 = GATHER ? (long)gidx[m0 + rA1] : (long)(m0 + rA1);
  const bf16*  hA0 = (const bf16*)Av + ga0 * (long)lda + ck;
  const bf16*  hA1 = (const bf16*)Av + ga1 * (long)lda + ck;
  const float* qA0 = (const float*)Av + ga0 * (long)lda + ck;
  const float* qA1 = (const float*)Av + ga1 * (long)lda + ck;
  const bf16*  pB0 = Bt + (long)(n0 + rA0) * K + ck;
  const bf16*  pB1 = Bt + (long)(n0 + rA1) * K + ck;

  bf16* lA0 = &As[seg0 * 512 + lane * 8];
  bf16* lA1 = &As[seg1 * 512 + lane * 8];
  bf16* lB0 = &Bs[seg0 * 512 + lane * 8];
  bf16* lB1 = &Bs[seg1 * 512 + lane * 8];

  f32x4 acc[4][4];
#pragma unroll
  for (int i = 0; i < 4; i++)
#pragma unroll
    for (int j = 0; j < 4; j++)
#pragma unroll
      for (int r = 0; r < 4; r++) acc[i][j][r] = 0.0f;

  const int mBase = (wave >> 1) * 64;
  const int nBase = (wave & 1) * 64;
  const int fr = lane & 15;
  const int fq = (lane >> 4) * 8;

  for (int k0 = 0; k0 < K; k0 += 32) {
    bf16x8 va0, va1;
    if (GATHER && af) {
      float4 a0 = *(const float4*)(qA0 + k0);
      float4 a1 = *(const float4*)(qA0 + k0 + 4);
      float4 b0 = *(const float4*)(qA1 + k0);
      float4 b1 = *(const float4*)(qA1 + k0 + 4);
      va0 = pack8(a0, a1);
      va1 = pack8(b0, b1);
    } else {
      va0 = *(const bf16x8*)(hA0 + k0);
      va1 = *(const bf16x8*)(hA1 + k0);
    }
    bf16x8 vb0 = *(const bf16x8*)(pB0 + k0);
    bf16x8 vb1 = *(const bf16x8*)(pB1 + k0);
    __syncthreads();
    *(bf16x8*)lA0 = va0;
    *(bf16x8*)lA1 = va1;
    *(bf16x8*)lB0 = vb0;
    *(bf16x8*)lB1 = vb1;
    __syncthreads();

    bf16x8 afr[4], bfr[4];
#pragma unroll
    for (int mt = 0; mt < 4; mt++)
      afr[mt] = *(const bf16x8*)&As[(mBase + mt * 16 + fr) * 32 + fq];
#pragma unroll
    for (int nt = 0; nt < 4; nt++)
      bfr[nt] = *(const bf16x8*)&Bs[(nBase + nt * 16 + fr) * 32 + fq];

#pragma unroll
    for (int mt = 0; mt < 4; mt++)
#pragma unroll
      for (int nt = 0; nt < 4; nt++)
        acc[mt][nt] = __builtin_amdgcn_mfma_f32_16x16x32_bf16(afr[mt], bfr[nt], acc[mt][nt], 0, 0, 0);
  }

  const int orow = (lane >> 4) * 4;
  const int ocol = lane & 15;
#pragma unroll
  for (int mt = 0; mt < 4; mt++) {
#pragma unroll
    for (int nt = 0; nt < 4; nt++) {
      int gr = m0 + mBase + mt * 16 + orow;
      int gc = n0 + nBase + nt * 16 + ocol;
      float bv = BIAS ? bias[gc] : 0.0f;
#pragma unroll
      for (int r = 0; r < 4; r++) {
        float v = acc[mt][nt][r] + bv;
        Cout[(long)(gr + r) * ldc + gc] = (bf16)v;
      }
    }
  }
}

// ---------------------------------------------------------------- converters
__global__ __launch_bounds__(256)
void transpose_conv(const void* __restrict__ in, bf16* __restrict__ out,
                    const int* __restrict__ flag, int R, int C)
{
  __shared__ float tile[32][33];
  int f = *flag;
  int x = blockIdx.x * 32 + threadIdx.x;
  int yb = blockIdx.y * 32;
#pragma unroll
  for (int i = threadIdx.y; i < 32; i += 8) {
    long idx = (long)(yb + i) * C + x;
    tile[i][threadIdx.x] = f ? ((const float*)in)[idx] : (float)((const bf16*)in)[idx];
  }
  __syncthreads();
  int x2 = yb + threadIdx.x;
  int y2b = blockIdx.x * 32;
#pragma unroll
  for (int i = threadIdx.y; i < 32; i += 8)
    out[(long)(y2b + i) * R + x2] = (bf16)tile[threadIdx.x][i];
}

// dual-base transpose+convert: picks f32 or bf16 source per flag
__global__ __launch_bounds__(256)
void transpose_conv2(const void* __restrict__ in32, const void* __restrict__ in16,
                     bf16* __restrict__ out, const int* __restrict__ flag, int R, int C)
{
  __shared__ float tile[32][33];
  int f = *flag;
  int x = blockIdx.x * 32 + threadIdx.x;
  int yb = blockIdx.y * 32;
#pragma unroll
  for (int i = threadIdx.y; i < 32; i += 8) {
    long idx = (long)(yb + i) * C + x;
    tile[i][threadIdx.x] = f ? ((const float*)in32)[idx] : (float)((const bf16*)in16)[idx];
  }
  __syncthreads();
  int x2 = yb + threadIdx.x;
  int y2b = blockIdx.x * 32;
#pragma unroll
  for (int i = threadIdx.y; i < 32; i += 8)
    out[(long)(y2b + i) * R + x2] = (bf16)tile[threadIdx.x][i];
}

__global__ __launch_bounds__(256)
void conv_to_f32(const void* __restrict__ in, float* __restrict__ out,
                 const int* __restrict__ flag, int n)
{
  int i = blockIdx.x * blockDim.x + threadIdx.x;
  if (i >= n) return;
  out[i] = (*flag) ? ((const float*)in)[i] : (float)((const bf16*)in)[i];
}

// ---------------------------------------------------------------- scan
// HG: bf16 [nseq*S_LEN, 2048]; cols 0..1023 hidden, 1024..2047 gate.
// Vectorized: each thread owns 4 channels; ushort4 (8B) loads per timestep.
// block = one (seq,chunk): grid = nseq*SCAN_C, 256 threads (1024ch/4).
__global__ __launch_bounds__(256)
void scan_pass1(const bf16* __restrict__ HG, float* __restrict__ Ab, float* __restrict__ Pb)
{
  const int bid = blockIdx.x;            // b*SCAN_C + j  (chunks contiguous in rows)
  const int c4  = threadIdx.x;           // channels c4*4 .. +3
  const unsigned short* base =
      (const unsigned short*)HG + (long)bid * SCAN_T * 2048 + c4 * 4;
  float A0 = 1.f, A1 = 1.f, A2 = 1.f, A3 = 1.f;
  float P0 = 0.f, P1 = 0.f, P2 = 0.f, P3 = 0.f;
#pragma unroll 4
  for (int t = 0; t < SCAN_T; t++) {
    ushort4 hv = *(const ushort4*)(base + (long)t * 2048);
    ushort4 gv = *(const ushort4*)(base + (long)t * 2048 + 1024);
    float a, v;
    av_calc(bs2f(hv.x), bs2f(gv.x), a, v); A0 *= a; P0 = fmaf(a, P0, v);
    av_calc(bs2f(hv.y), bs2f(gv.y), a, v); A1 *= a; P1 = fmaf(a, P1, v);
    av_calc(bs2f(hv.z), bs2f(gv.z), a, v); A2 *= a; P2 = fmaf(a, P2, v);
    av_calc(bs2f(hv.w), bs2f(gv.w), a, v); A3 *= a; P3 = fmaf(a, P3, v);
  }
  long o = ((long)bid << 10) + c4 * 4;
  *(float4*)(Ab + o) = make_float4(A0, A1, A2, A3);
  *(float4*)(Pb + o) = make_float4(P0, P1, P2, P3);
}

__global__ __launch_bounds__(256)
void scan_pass2(const float* __restrict__ Ab, float* __restrict__ Pb)
{
  int tid = blockIdx.x * blockDim.x + threadIdx.x;
  int c = tid & (HIDIM - 1);
  int b = tid >> 10;
  float h = 0.0f;
  for (int j = 0; j < SCAN_C; j++) {
    long i = ((long)(b * SCAN_C + j) << 10) + c;
    float A = Ab[i];
    float P = Pb[i];
    Pb[i] = h;
    h = fmaf(A, h, P);
  }
}

__global__ __launch_bounds__(256)
void scan_pass3(bf16* __restrict__ HG, const float* __restrict__ Pb)
{
  const int bid = blockIdx.x;
  const int c4  = threadIdx.x;
  unsigned short* base =
      (unsigned short*)HG + (long)bid * SCAN_T * 2048 + c4 * 4;
  long o = ((long)bid << 10) + c4 * 4;
  float4 hin = *(const float4*)(Pb + o);
  float h0 = hin.x, h1 = hin.y, h2 = hin.z, h3 = hin.w;
#pragma unroll 4
  for (int t = 0; t < SCAN_T; t++) {
    ushort4 hv = *(const ushort4*)(base + (long)t * 2048);
    ushort4 gv = *(const ushort4*)(base + (long)t * 2048 + 1024);
    float a, v;
    av_calc(bs2f(hv.x), bs2f(gv.x), a, v); h0 = fmaf(a, h0, v);
    av_calc(bs2f(hv.y), bs2f(gv.y), a, v); h1 = fmaf(a, h1, v);
    av_calc(bs2f(hv.z), bs2f(gv.z), a, v); h2 = fmaf(a, h2, v);
    av_calc(bs2f(hv.w), bs2f(gv.w), a, v); h3 = fmaf(a, h3, v);
    ushort4 w;
    w.x = (unsigned short)f2bs(h0);
    w.y = (unsigned short)f2bs(h1);
    w.z = (unsigned short)f2bs(h2);
    w.w = (unsigned short)f2bs(h3);
    *(ushort4*)(base + (long)t * 2048) = w;   // h lives in hidden cols
  }
}

// ---------------------------------------------------------------- shift / output
__global__ __launch_bounds__(256)
void rev_build(const bf16* __restrict__ X, bf16* __restrict__ X2, const int* __restrict__ lens)
{
  int bt = blockIdx.x;
  int b = bt >> 11;
  int t = bt & (S_LEN - 1);
  int pad = S_LEN - lens[b];
  int src = S_LEN - 1 - ((t + pad) & (S_LEN - 1));
  const u32* s = (const u32*)(X + (long)(b * S_LEN + src) * HDIM);
  u32* d = (u32*)(X2 + (long)(b * S_LEN + t) * HDIM);
  d[threadIdx.x] = s[threadIdx.x];
}

__global__ __launch_bounds__(256)
void finalize_out(const bf16* __restrict__ X, const bf16* __restrict__ X2,
                  const int* __restrict__ lens, const int* __restrict__ flag,
                  void* __restrict__ out)
{
  int bt = blockIdx.x;
  int b = bt >> 11;
  int t = bt & (S_LEN - 1);
  int pad = S_LEN - lens[b];
  int src = S_LEN - 1 - ((t + pad) & (S_LEN - 1));
  const bf16* sf = X  + (long)(b * S_LEN + t) * HDIM;
  const bf16* sr = X2 + (long)(b * S_LEN + src) * HDIM;
  long ro = (long)(b * S_LEN + t) * 1024;
  if (*flag) {
    float* d = (float*)out + ro;
    for (int c = threadIdx.x; c < 512; c += 256) {
      d[c]       = (float)sf[c];
      d[512 + c] = (float)sr[c];
    }
  } else {
    bf16* d = (bf16*)out + ro;
    for (int c = threadIdx.x; c < 512; c += 256) {
      d[c]       = sf[c];
      d[512 + c] = sr[c];
    }
  }
}

__global__ __launch_bounds__(256)
void seq_out_k(const bf16* __restrict__ X, const bf16* __restrict__ X2,
               const int* __restrict__ lens, const int* __restrict__ flag,
               void* __restrict__ out)
{
  int b = blockIdx.x;
  int t = lens[b] - 1;
  const bf16* sf = X  + (long)(b * S_LEN + t) * HDIM;
  const bf16* sr = X2 + (long)(b * S_LEN + 0) * HDIM;
  long off = (long)BATCH * S_LEN * 1024 + (long)b * 1024;
  if (*flag) {
    float* d = (float*)out + off;
    for (int c = threadIdx.x; c < 512; c += 256) {
      d[c]       = (float)sf[c];
      d[512 + c] = (float)sr[c];
    }
  } else {
    bf16* d = (bf16*)out + off;
    for (int c = threadIdx.x; c < 512; c += 256) {
      d[c]       = sf[c];
      d[512 + c] = sr[c];
    }
  }
}

// ---------------------------------------------------------------- launch
extern "C" void kernel_launch(void* const* d_in, const int* in_sizes, int n_in,
                              void* d_out, int out_size, void* d_ws, size_t ws_size,
                              hipStream_t stream)
{
  (void)in_sizes; (void)n_in; (void)out_size;
  const int* x_source = (const int*)d_in[0];
  const int* x_len    = (const int*)d_in[1];
  const void* emb     = d_in[2];
  const void* W_er    = d_in[3];
  const void* b_er    = d_in[4];
  const void* W_hg[2]  = { d_in[5], d_in[7] };   // [3,512,2048]
  const void* W_out[2] = { d_in[6], d_in[8] };   // [3,1024,512]

  char* ws = (char*)d_ws;
  size_t off = 0;
  auto alloc = [&](size_t bytes) -> char* {
    char* p = ws + off;
    off += (bytes + 255) & ~(size_t)255;
    return p;
  };
  auto a256 = [](size_t b) -> size_t { return (b + 255) & ~(size_t)255; };

  int*   flag = (int*)  alloc(256);
  float* berF = (float*)alloc(512 * 4);
  bf16*  WerT = (bf16*) alloc((size_t)512 * 512 * 2);
  bf16*  X    = (bf16*) alloc((size_t)BATCH * S_LEN * HDIM * 2);   // fwd acts, 32 MB
  bf16*  X2   = (bf16*) alloc((size_t)BATCH * S_LEN * HDIM * 2);   // rev acts, 32 MB
  bf16* WhgT[2][NLAYER];
  bf16* WoutT[2][NLAYER];
  for (int d = 0; d < 2; d++)
    for (int l = 0; l < NLAYER; l++) {
      WhgT[d][l]  = (bf16*)alloc((size_t)2048 * 512 * 2);
      WoutT[d][l] = (bf16*)alloc((size_t)512 * 1024 * 2);
    }

  // virtual dir-seq space: 32 sequences (dir0 = seqs 0..15 in X, dir1 = 16..31 in X2).
  // chunk of bchv dir-seqs processed per GEMM/scan round; bchv=32 fuses both dirs.
  size_t fixedEnd = off;
  int bchv = 32;
  while (bchv > 1) {
    size_t need = fixedEnd
      + a256((size_t)bchv * S_LEN * 2048 * 2)
      + 2 * a256((size_t)bchv * SCAN_C * HIDIM * 4);
    if (need <= ws_size) break;
    bchv >>= 1;
  }
  bf16*  HG = (bf16*) alloc((size_t)bchv * S_LEN * 2048 * 2);
  float* Ab = (float*)alloc((size_t)bchv * SCAN_C * HIDIM * 4);
  float* Pb = (float*)alloc((size_t)bchv * SCAN_C * HIDIM * 4);

  probe_dtype<<<1, 64, 0, stream>>>((const unsigned short*)emb, flag);

  conv_to_f32<<<2, 256, 0, stream>>>(b_er, berF, flag, 512);
  dim3 tb(32, 8);
  transpose_conv<<<dim3(16, 16), tb, 0, stream>>>(W_er, WerT, flag, 512, 512);
  for (int d = 0; d < 2; d++)
    for (int l = 0; l < NLAYER; l++) {
      const char* hg32 = (const char*)W_hg[d] + (size_t)l * 512 * 2048 * 4;
      const char* hg16 = (const char*)W_hg[d] + (size_t)l * 512 * 2048 * 2;
      const char* wo32 = (const char*)W_out[d] + (size_t)l * 1024 * 512 * 4;
      const char* wo16 = (const char*)W_out[d] + (size_t)l * 1024 * 512 * 2;
      transpose_conv2<<<dim3(2048 / 32, 512 / 32), tb, 0, stream>>>(hg32, hg16, WhgT[d][l], flag, 512, 2048);
      transpose_conv2<<<dim3(512 / 32, 1024 / 32), tb, 0, stream>>>(wo32, wo16, WoutT[d][l], flag, 1024, 512);
    }

  // x_emb = emb[x_source] @ W_er + b_er -> X (bf16)   (gather path, dtype via flag)
  gemm_mfma<1, 1><<<dim3(4, (BATCH * S_LEN) / 128), 256, 0, stream>>>(
      emb, WerT, X, berF, x_source, flag, BATCH * S_LEN, 512, 512, 512, 512);

  rev_build<<<BATCH * S_LEN, 256, 0, stream>>>(X, X2, x_len);

  const int nchunk = 32 / bchv;
  for (int l = 0; l < NLAYER; l++) {
    for (int cb = 0; cb < nchunk; cb++) {
      const int s0    = cb * bchv;          // first dir-seq of chunk
      const int Mrows = bchv * S_LEN;
      // chunk straddles dirs only when bchv==32 (split at row 16*S_LEN)
      int mHalf;
      bf16 *Xa, *Xa2; const bf16 *Bh, *Bh2, *Bo, *Bo2;
      if (bchv == 32) {
        mHalf = 16 * S_LEN;
        Xa  = X;  Xa2 = X2;
        Bh  = WhgT[0][l];  Bh2 = WhgT[1][l];
        Bo  = WoutT[0][l]; Bo2 = WoutT[1][l];
      } else {
        const int dir = s0 >> 4;            // chunk entirely within one dir
        mHalf = Mrows;                      // never splits
        Xa  = (dir ? X2 : X) + (size_t)(s0 & 15) * S_LEN * HDIM;
        Xa2 = Xa;
        Bh  = WhgT[dir][l];  Bh2 = Bh;
        Bo  = WoutT[dir][l]; Bo2 = Bo;
      }
      // HG = Xa @ W_hg   [Mrows,512] x [512,2048]
      gemm8<<<dim3(2048 / 256, Mrows / 256), 512, 131072, stream>>>(
          Xa, Xa2, Bh, Bh2, HG, HG + (size_t)mHalf * 2048, 512, 512, 2048, mHalf);
      scan_pass1<<<bchv * SCAN_C, 256, 0, stream>>>(HG, Ab, Pb);
      scan_pass2<<<(bchv * HIDIM) / 256, 256, 0, stream>>>(Ab, Pb);
      scan_pass3<<<bchv * SCAN_C, 256, 0, stream>>>(HG, Pb);
      // Xa = h @ W_out   [Mrows,1024(stride 2048)] x [1024,512]
      gemm8<<<dim3(512 / 256, Mrows / 256), 512, 131072, stream>>>(
          HG, HG + (size_t)mHalf * 2048, Bo, Bo2, Xa, Xa2, 1024, 2048, 512, mHalf);
    }
  }

  finalize_out<<<BATCH * S_LEN, 256, 0, stream>>>(X, X2, x_len, flag, d_out);
  seq_out_k<<<BATCH, 256, 0, stream>>>(X, X2, x_len, flag, d_out);
}